// Round 2
// baseline (1694.042 us; speedup 1.0000x reference)
//
#include <hip/hip_runtime.h>
#include <math.h>

// Problem constants (match reference)
constexpr int kB   = 2;
constexpr int kT   = 2048;
constexpr int kDIN = 2048;
constexpr int kD   = 512;
constexpr int kH   = 8;
constexpr int kHD  = 64;
constexpr int kNB  = 2;
constexpr int kM   = kB * kT;   // 4096 rows

// ---------------------------------------------------------------------------
// Rope table: tab[(t*32+f)*2] = cos(t * 10000^(-f/32)), [..+1] = sin(...)
// Built in double precision once per call (65536 threads, trivial cost).
// ---------------------------------------------------------------------------
__global__ __launch_bounds__(256) void rope_table_kernel(float* __restrict__ tab) {
    int idx = blockIdx.x * blockDim.x + threadIdx.x; // t*32 + f
    if (idx >= kT * 32) return;
    int t = idx >> 5, f = idx & 31;
    double inv = pow(10000.0, -(double)f / 32.0);
    double ang = (double)t * inv;
    tab[idx * 2]     = (float)cos(ang);
    tab[idx * 2 + 1] = (float)sin(ang);
}

// ---------------------------------------------------------------------------
// Per-row mean / rstd for LayerNorm. One 256-thread block per row.
// ---------------------------------------------------------------------------
__global__ __launch_bounds__(256) void row_stats_kernel(const float* __restrict__ A,
                                                        float* __restrict__ stats, int C) {
    int row = blockIdx.x;
    const float4* A4 = (const float4*)(A + (size_t)row * C);
    int nv = C >> 2;
    float s = 0.f, ss = 0.f;
    for (int i = threadIdx.x; i < nv; i += 256) {
        float4 v = A4[i];
        s  += v.x + v.y + v.z + v.w;
        ss += v.x * v.x + v.y * v.y + v.z * v.z + v.w * v.w;
    }
    #pragma unroll
    for (int o = 32; o > 0; o >>= 1) {
        s  += __shfl_down(s, o, 64);
        ss += __shfl_down(ss, o, 64);
    }
    __shared__ float ls[4], lss[4];
    int wid = threadIdx.x >> 6, lane = threadIdx.x & 63;
    if (lane == 0) { ls[wid] = s; lss[wid] = ss; }
    __syncthreads();
    if (threadIdx.x == 0) {
        float S = ls[0] + ls[1] + ls[2] + ls[3];
        float SS = lss[0] + lss[1] + lss[2] + lss[3];
        float mean = S / C;
        float var  = SS / C - mean * mean;
        stats[row * 2]     = mean;
        stats[row * 2 + 1] = rsqrtf(var + 1e-5f);
    }
}

// ---------------------------------------------------------------------------
// Tiled fp32 GEMM: C[M][N] = act( LN_opt(A) @ W + bias (+ res) )
// BM=BN=64, BK=16, 256 threads, 4x4 micro-tile per thread.
// LN applied on A-tile load (per-row mean/rstd from stats, per-col g/b).
// N may be < 64 (fc2, N=32) -> guarded.
// ---------------------------------------------------------------------------
template <bool LN, bool RELU, bool RES>
__global__ __launch_bounds__(256) void gemm_kernel(
    const float* __restrict__ A, const float* __restrict__ W,
    const float* __restrict__ bias, const float* __restrict__ stats,
    const float* __restrict__ lnG, const float* __restrict__ lnB,
    const float* __restrict__ res, float* __restrict__ Cout,
    int K, int N) {
    __shared__ __align__(16) float As[16][68];
    __shared__ __align__(16) float Bs[16][68];
    int tid = threadIdx.x;
    int bm = blockIdx.y, bn = blockIdx.x;
    int tm = tid >> 4, tn = tid & 15;

    // A-load mapping: 64 rows x 16 k, one float4 per thread
    int am   = tid >> 2;            // 0..63
    int ak4  = (tid & 3) << 2;      // 0,4,8,12
    int arow = bm * 64 + am;
    float mean = 0.f, rstd = 0.f;
    if (LN) { mean = stats[arow * 2]; rstd = stats[arow * 2 + 1]; }

    // B-load mapping: 16 k x 64 n, one float4 per thread
    int bk   = tid >> 4;            // 0..15
    int bn4  = (tid & 15) << 2;     // 0..60
    int bcol = bn * 64 + bn4;

    float acc[4][4] = {};

    for (int k0 = 0; k0 < K; k0 += 16) {
        float4 a = *(const float4*)(A + (size_t)arow * K + k0 + ak4);
        if (LN) {
            float4 gv = *(const float4*)(lnG + k0 + ak4);
            float4 bv = *(const float4*)(lnB + k0 + ak4);
            a.x = (a.x - mean) * rstd * gv.x + bv.x;
            a.y = (a.y - mean) * rstd * gv.y + bv.y;
            a.z = (a.z - mean) * rstd * gv.z + bv.z;
            a.w = (a.w - mean) * rstd * gv.w + bv.w;
        }
        As[ak4 + 0][am] = a.x;
        As[ak4 + 1][am] = a.y;
        As[ak4 + 2][am] = a.z;
        As[ak4 + 3][am] = a.w;

        float4 b = make_float4(0.f, 0.f, 0.f, 0.f);
        if (bcol < N) b = *(const float4*)(W + (size_t)(k0 + bk) * N + bcol);
        *(float4*)&Bs[bk][bn4] = b;

        __syncthreads();
        #pragma unroll
        for (int kk = 0; kk < 16; ++kk) {
            float4 av = *(const float4*)&As[kk][tm << 2];
            float4 bv = *(const float4*)&Bs[kk][tn << 2];
            acc[0][0] += av.x * bv.x; acc[0][1] += av.x * bv.y; acc[0][2] += av.x * bv.z; acc[0][3] += av.x * bv.w;
            acc[1][0] += av.y * bv.x; acc[1][1] += av.y * bv.y; acc[1][2] += av.y * bv.z; acc[1][3] += av.y * bv.w;
            acc[2][0] += av.z * bv.x; acc[2][1] += av.z * bv.y; acc[2][2] += av.z * bv.z; acc[2][3] += av.z * bv.w;
            acc[3][0] += av.w * bv.x; acc[3][1] += av.w * bv.y; acc[3][2] += av.w * bv.z; acc[3][3] += av.w * bv.w;
        }
        __syncthreads();
    }

    int crow0 = bm * 64 + (tm << 2);
    int ccol0 = bn * 64 + (tn << 2);
    if (ccol0 < N) {
        float4 bs = *(const float4*)(bias + ccol0);
        #pragma unroll
        for (int i = 0; i < 4; ++i) {
            float4 c = make_float4(acc[i][0] + bs.x, acc[i][1] + bs.y,
                                   acc[i][2] + bs.z, acc[i][3] + bs.w);
            if (RES) {
                float4 r = *(const float4*)(res + (size_t)(crow0 + i) * N + ccol0);
                c.x += r.x; c.y += r.y; c.z += r.z; c.w += r.w;
            }
            if (RELU) {
                c.x = fmaxf(c.x, 0.f); c.y = fmaxf(c.y, 0.f);
                c.z = fmaxf(c.z, 0.f); c.w = fmaxf(c.w, 0.f);
            }
            *(float4*)(Cout + (size_t)(crow0 + i) * N + ccol0) = c;
        }
    }
}

// ---------------------------------------------------------------------------
// Rope (in-place) on q and k buffers, exact reference convention:
// pair (2i,2i+1) head-local; rot[2i] = -x[2i+1], rot[2i+1] = x[2i];
// freq index f(d) = (d&63)<32 ? d&63 : (d&63)-32  (note: differs for the
// two elements of a pair).
// ---------------------------------------------------------------------------
__global__ __launch_bounds__(256) void rope_kernel(float* __restrict__ q, float* __restrict__ k,
                                                   const float* __restrict__ tab) {
    int idx = blockIdx.x * blockDim.x + threadIdx.x;  // pair index
    if (idx >= kM * (kD / 2)) return;
    int row = idx >> 8;          // D/2 = 256 pairs per row
    int pi  = idx & 255;
    int col = pi << 1;
    int t   = row & (kT - 1);
    int dl  = col & 63;
    int f0  = (dl < 32) ? dl : dl - 32;
    int f1  = f0 + 1;            // dl even => same half for dl+1
    const float* tb = tab + (size_t)t * 64;   // 32 freqs * 2
    float c0 = tb[f0 * 2], s0 = tb[f0 * 2 + 1];
    float c1 = tb[f1 * 2], s1 = tb[f1 * 2 + 1];
    size_t g = (size_t)row * kD + col;
    float2 qv = *(float2*)(q + g);
    float2 kv = *(float2*)(k + g);
    float2 qo = make_float2(qv.x * c0 - qv.y * s0, qv.y * c1 + qv.x * s1);
    float2 ko = make_float2(kv.x * c0 - kv.y * s0, kv.y * c1 + kv.x * s1);
    *(float2*)(q + g) = qo;
    *(float2*)(k + g) = ko;
}

// ---------------------------------------------------------------------------
// Adapter K/V rows (tiny GEMVs): 12 workgroups (B * 6 rows).
// which: 0=ka pos0(h_a), 1=ka pos1(p, rope t=1), 2=va pos0, 3=va pos1,
//        4=kt (scaled by tanh(g)), 5=vt
// ---------------------------------------------------------------------------
__global__ __launch_bounds__(256) void adapter_kernel(
    const float* __restrict__ h_a, const float* __restrict__ h_t, const float* __restrict__ p,
    const float* __restrict__ kaW, const float* __restrict__ kab,
    const float* __restrict__ vaW, const float* __restrict__ vab,
    const float* __restrict__ ktW, const float* __restrict__ ktb,
    const float* __restrict__ vtW, const float* __restrict__ vtb,
    const float* __restrict__ gscal, const float* __restrict__ tab,
    float* __restrict__ ka, float* __restrict__ va,
    float* __restrict__ kt, float* __restrict__ vt, int blk) {
    __shared__ float in[kD];
    int wg = blockIdx.x;
    int b = wg / 6, which = wg % 6;
    const float* ha_row = h_a + ((size_t)b * (kNB + 1) + blk + 1) * kD;
    const float* ht_row = h_t + ((size_t)b * (kNB + 1) + blk + 1) * kD;
    const float* p_row  = p + (size_t)b * kD;
    const float* inrow; const float* W; const float* bias; float* outrow;
    switch (which) {
        case 0: inrow = ha_row; W = kaW; bias = kab; outrow = ka + (size_t)(b * 2 + 0) * kD; break;
        case 1: inrow = p_row;  W = kaW; bias = kab; outrow = ka + (size_t)(b * 2 + 1) * kD; break;
        case 2: inrow = ha_row; W = vaW; bias = vab; outrow = va + (size_t)(b * 2 + 0) * kD; break;
        case 3: inrow = p_row;  W = vaW; bias = vab; outrow = va + (size_t)(b * 2 + 1) * kD; break;
        case 4: inrow = ht_row; W = ktW; bias = ktb; outrow = kt + (size_t)b * kD; break;
        default: inrow = ht_row; W = vtW; bias = vtb; outrow = vt + (size_t)b * kD; break;
    }
    W += (size_t)blk * kD * kD;
    bias += (size_t)blk * kD;
    int tid = threadIdx.x;
    in[tid * 2]     = inrow[tid * 2];
    in[tid * 2 + 1] = inrow[tid * 2 + 1];
    __syncthreads();
    float a0 = 0.f, a1 = 0.f;
    int c0 = tid * 2;
    for (int kk = 0; kk < kD; ++kk) {
        float x = in[kk];
        float2 w = *(const float2*)(W + (size_t)kk * kD + c0);
        a0 += x * w.x; a1 += x * w.y;
    }
    a0 += bias[c0]; a1 += bias[c0 + 1];
    if (which == 1) {           // rope t=1 on this pair
        int dl = c0 & 63;
        int f0 = (dl < 32) ? dl : dl - 32;
        int f1 = f0 + 1;
        const float* tb = tab + (size_t)1 * 64;
        float cc0 = tb[f0 * 2], ss0 = tb[f0 * 2 + 1];
        float cc1 = tb[f1 * 2], ss1 = tb[f1 * 2 + 1];
        float n0 = a0 * cc0 - a1 * ss0;
        float n1 = a1 * cc1 + a0 * ss1;
        a0 = n0; a1 = n1;
    }
    if (which == 4) {           // fold tanh(g) into kt (score linear in kt)
        float r = tanhf(gscal[blk]);
        a0 *= r; a1 *= r;
    }
    outrow[c0] = a0; outrow[c0 + 1] = a1;
}

// ---------------------------------------------------------------------------
// Flash-style attention, fp32. Grid: (T/32, H, B). 256 threads.
// 32 queries per WG; 33 key tiles: 32 x 64 sequence keys + 1 tail tile of 3
// adapter/task keys (ka0, ka1, kt*tanh(g)).
// Thread (qi = tid>>3, l8 = tid&7): scores for keys j = jj*8 + l8,
// output dims d = l8*8 .. +7. 1/sqrt(HD)=1/8 folded into staged Q.
// ---------------------------------------------------------------------------
__global__ __launch_bounds__(256) void attn_kernel(
    const float* __restrict__ q, const float* __restrict__ k, const float* __restrict__ v,
    const float* __restrict__ ka, const float* __restrict__ va,
    const float* __restrict__ kt, const float* __restrict__ vt,
    float* __restrict__ out) {
    __shared__ __align__(16) float Qs[32][68];
    __shared__ __align__(16) float Ks[64][68];
    __shared__ __align__(16) float Vs[64][68];
    __shared__ __align__(16) float Ps[32][68];
    int tid = threadIdx.x;
    int tq0 = blockIdx.x * 32;
    int h   = blockIdx.y;
    int b   = blockIdx.z;
    int qi = tid >> 3, l8 = tid & 7;
    int d0 = l8 * 8;

    // stage Q (scaled by 1/8)
    {
        int f4 = tid;
        #pragma unroll
        for (int it = 0; it < 2; ++it, f4 += 256) {
            int r = f4 >> 4, c4 = (f4 & 15) << 2;
            float4 qv = *(const float4*)(q + ((size_t)(b * kT + tq0 + r) * kD) + h * kHD + c4);
            qv.x *= 0.125f; qv.y *= 0.125f; qv.z *= 0.125f; qv.w *= 0.125f;
            *(float4*)&Qs[r][c4] = qv;
        }
    }

    float m = -1e30f, l = 0.f;
    float acc[8] = {};

    for (int tile = 0; tile <= 32; ++tile) {
        __syncthreads();   // protect K/V/P LDS from previous iteration readers
        if (tile < 32) {
            int f4 = tid;
            #pragma unroll
            for (int it = 0; it < 4; ++it, f4 += 256) {
                int r = f4 >> 4, c4 = (f4 & 15) << 2;
                size_t g = ((size_t)(b * kT + tile * 64 + r) * kD) + h * kHD + c4;
                *(float4*)&Ks[r][c4] = *(const float4*)(k + g);
                *(float4*)&Vs[r][c4] = *(const float4*)(v + g);
            }
        } else {
            int f4 = tid;   // 3 rows * 16 float4s = 48
            if (f4 < 48) {
                int r = f4 >> 4, c4 = (f4 & 15) << 2;
                const float* kr; const float* vr;
                if (r < 2) {
                    kr = ka + (size_t)(b * 2 + r) * kD + h * kHD;
                    vr = va + (size_t)(b * 2 + r) * kD + h * kHD;
                } else {
                    kr = kt + (size_t)b * kD + h * kHD;
                    vr = vt + (size_t)b * kD + h * kHD;
                }
                *(float4*)&Ks[r][c4] = *(const float4*)(kr + c4);
                *(float4*)&Vs[r][c4] = *(const float4*)(vr + c4);
            }
        }
        __syncthreads();

        // scores: 8 keys per thread, full 64-dim dot
        float s[8];
        #pragma unroll
        for (int jj = 0; jj < 8; ++jj) s[jj] = 0.f;
        #pragma unroll
        for (int d4 = 0; d4 < 16; ++d4) {
            float4 qv = *(const float4*)&Qs[qi][d4 << 2];
            #pragma unroll
            for (int jj = 0; jj < 8; ++jj) {
                float4 kv = *(const float4*)&Ks[jj * 8 + l8][d4 << 2];
                s[jj] += qv.x * kv.x + qv.y * kv.y + qv.z * kv.z + qv.w * kv.w;
            }
        }
        if (tile == 32) {
            #pragma unroll
            for (int jj = 0; jj < 8; ++jj)
                if (jj * 8 + l8 >= 3) s[jj] = -1e30f;
        }

        // online softmax over this tile
        float tmx = s[0];
        #pragma unroll
        for (int jj = 1; jj < 8; ++jj) tmx = fmaxf(tmx, s[jj]);
        tmx = fmaxf(tmx, __shfl_xor(tmx, 1, 64));
        tmx = fmaxf(tmx, __shfl_xor(tmx, 2, 64));
        tmx = fmaxf(tmx, __shfl_xor(tmx, 4, 64));
        float nm = fmaxf(m, tmx);
        float alpha = __expf(m - nm);
        float ps = 0.f;
        #pragma unroll
        for (int jj = 0; jj < 8; ++jj) { s[jj] = __expf(s[jj] - nm); ps += s[jj]; }
        ps += __shfl_xor(ps, 1, 64);
        ps += __shfl_xor(ps, 2, 64);
        ps += __shfl_xor(ps, 4, 64);
        l = l * alpha + ps;
        m = nm;
        #pragma unroll
        for (int d = 0; d < 8; ++d) acc[d] *= alpha;
        #pragma unroll
        for (int jj = 0; jj < 8; ++jj) Ps[qi][jj * 8 + l8] = s[jj];
        __syncthreads();

        // PV accumulate
        int nk = (tile < 32) ? 64 : 3;
        for (int j = 0; j < nk; ++j) {
            float pw = Ps[qi][j];
            float4 v0 = *(const float4*)&Vs[j][d0];
            float4 v1 = *(const float4*)&Vs[j][d0 + 4];
            acc[0] += pw * v0.x; acc[1] += pw * v0.y; acc[2] += pw * v0.z; acc[3] += pw * v0.w;
            acc[4] += pw * v1.x; acc[5] += pw * v1.y; acc[6] += pw * v1.z; acc[7] += pw * v1.w;
        }
    }

    float invl = 1.f / l;
    size_t g = ((size_t)(b * kT + tq0 + qi) * kD) + h * kHD + d0;
    float4 o0 = make_float4(acc[0] * invl, acc[1] * invl, acc[2] * invl, acc[3] * invl);
    float4 o1 = make_float4(acc[4] * invl, acc[5] * invl, acc[6] * invl, acc[7] * invl);
    *(float4*)(out + g) = o0;
    *(float4*)(out + g + 4) = o1;
}

// ---------------------------------------------------------------------------
extern "C" void kernel_launch(void* const* d_in, const int* in_sizes, int n_in,
                              void* d_out, int out_size, void* d_ws, size_t ws_size,
                              hipStream_t stream) {
    const float* x      = (const float*)d_in[0];
    const float* h_a    = (const float*)d_in[1];
    const float* h_t    = (const float*)d_in[2];
    const float* p      = (const float*)d_in[3];
    const float* ln1_g  = (const float*)d_in[4];
    const float* ln1_b  = (const float*)d_in[5];
    const float* fc1_W  = (const float*)d_in[6];
    const float* fc1_b  = (const float*)d_in[7];
    const float* blk_qW  = (const float*)d_in[8];
    const float* blk_qb  = (const float*)d_in[9];
    const float* blk_ksW = (const float*)d_in[10];
    const float* blk_ksb = (const float*)d_in[11];
    const float* blk_vsW = (const float*)d_in[12];
    const float* blk_vsb = (const float*)d_in[13];
    const float* blk_kaW = (const float*)d_in[14];
    const float* blk_kab = (const float*)d_in[15];
    const float* blk_vaW = (const float*)d_in[16];
    const float* blk_vab = (const float*)d_in[17];
    const float* blk_ktW = (const float*)d_in[18];
    const float* blk_ktb = (const float*)d_in[19];
    const float* blk_vtW = (const float*)d_in[20];
    const float* blk_vtb = (const float*)d_in[21];
    const float* blk_oW  = (const float*)d_in[22];
    const float* blk_ob  = (const float*)d_in[23];
    const float* blk_g   = (const float*)d_in[24];
    const float* blk_lnG = (const float*)d_in[25];
    const float* blk_lnB = (const float*)d_in[26];
    const float* blk_fW  = (const float*)d_in[27];
    const float* blk_fb  = (const float*)d_in[28];
    const float* ln2_g  = (const float*)d_in[29];
    const float* ln2_b  = (const float*)d_in[30];
    const float* fc2_W  = (const float*)d_in[31];
    const float* fc2_b  = (const float*)d_in[32];
    float* out = (float*)d_out;

    // Workspace layout (floats). Total ~10.64M floats = 42.5 MB.
    float* ws = (float*)d_ws;
    size_t o = 0;
    float* rope_tab = ws + o; o += (size_t)kT * 32 * 2;     // 131072
    float* stats    = ws + o; o += (size_t)kM * 2;          // 8192
    float* bufX     = ws + o; o += (size_t)kM * kD;         // x0 / x1 / x2
    float* bufQ     = ws + o; o += (size_t)kM * kD;
    float* bufK     = ws + o; o += (size_t)kM * kD;         // also y (o-proj out)
    float* bufV     = ws + o; o += (size_t)kM * kD;
    float* bufAO    = ws + o; o += (size_t)kM * kD;         // attention output
    float* ka_buf   = ws + o; o += (size_t)kB * 2 * kD;
    float* va_buf   = ws + o; o += (size_t)kB * 2 * kD;
    float* kt_buf   = ws + o; o += (size_t)kB * kD;
    float* vt_buf   = ws + o; o += (size_t)kB * kD;

    dim3 blk256(256);
    dim3 gemm_grid(kD / 64, kM / 64);        // (8, 64)
    dim3 fc2_grid(1, kM / 64);               // N=32
    dim3 attn_grid(kT / 32, kH, kB);         // (64, 8, 2)

    // rope tables
    rope_table_kernel<<<(kT * 32 + 255) / 256, blk256, 0, stream>>>(rope_tab);

    // fc1: relu(LN(x) @ fc1_W + fc1_b)
    row_stats_kernel<<<kM, blk256, 0, stream>>>(x, stats, kDIN);
    gemm_kernel<true, true, false><<<gemm_grid, blk256, 0, stream>>>(
        x, fc1_W, fc1_b, stats, ln1_g, ln1_b, nullptr, bufX, kDIN, kD);

    for (int blk = 0; blk < kNB; ++blk) {
        const float* qW  = blk_qW  + (size_t)blk * kD * kD;
        const float* qb  = blk_qb  + (size_t)blk * kD;
        const float* ksW = blk_ksW + (size_t)blk * kD * kD;
        const float* ksb = blk_ksb + (size_t)blk * kD;
        const float* vsW = blk_vsW + (size_t)blk * kD * kD;
        const float* vsb = blk_vsb + (size_t)blk * kD;
        const float* oW  = blk_oW  + (size_t)blk * kD * kD;
        const float* ob  = blk_ob  + (size_t)blk * kD;
        const float* fW  = blk_fW  + (size_t)blk * kD * kD;
        const float* fb  = blk_fb  + (size_t)blk * kD;
        const float* lnG = blk_lnG + (size_t)blk * kD;
        const float* lnB = blk_lnB + (size_t)blk * kD;

        // QKV projections
        gemm_kernel<false, false, false><<<gemm_grid, blk256, 0, stream>>>(
            bufX, qW, qb, nullptr, nullptr, nullptr, nullptr, bufQ, kD, kD);
        gemm_kernel<false, false, false><<<gemm_grid, blk256, 0, stream>>>(
            bufX, ksW, ksb, nullptr, nullptr, nullptr, nullptr, bufK, kD, kD);
        gemm_kernel<false, false, false><<<gemm_grid, blk256, 0, stream>>>(
            bufX, vsW, vsb, nullptr, nullptr, nullptr, nullptr, bufV, kD, kD);

        // rope on q, ks
        rope_kernel<<<kM, blk256, 0, stream>>>(bufQ, bufK, rope_tab);

        // adapter / task K,V rows
        adapter_kernel<<<12, blk256, 0, stream>>>(
            h_a, h_t, p, blk_kaW, blk_kab, blk_vaW, blk_vab,
            blk_ktW, blk_ktb, blk_vtW, blk_vtb, blk_g, rope_tab,
            ka_buf, va_buf, kt_buf, vt_buf, blk);

        // attention
        attn_kernel<<<attn_grid, blk256, 0, stream>>>(
            bufQ, bufK, bufV, ka_buf, va_buf, kt_buf, vt_buf, bufAO);

        // o-proj + residual: y = AO @ oW + ob + x   (y -> bufK, K is dead)
        gemm_kernel<false, false, true><<<gemm_grid, blk256, 0, stream>>>(
            bufAO, oW, ob, nullptr, nullptr, nullptr, bufX, bufK, kD, kD);

        // FFN: x = relu(LN(y) @ fW + fb)
        row_stats_kernel<<<kM, blk256, 0, stream>>>(bufK, stats, kD);
        gemm_kernel<true, true, false><<<gemm_grid, blk256, 0, stream>>>(
            bufK, fW, fb, stats, lnG, lnB, nullptr, bufX, kD, kD);
    }

    // final: LN(x) @ fc2_W + fc2_b
    row_stats_kernel<<<kM, blk256, 0, stream>>>(bufX, stats, kD);
    gemm_kernel<true, false, false><<<fc2_grid, blk256, 0, stream>>>(
        bufX, fc2_W, fc2_b, stats, ln2_g, ln2_b, nullptr, out, kD, 32);
}

// Round 7
// 624.307 us; speedup vs baseline: 2.7135x; 2.7135x over previous
//
#include <hip/hip_runtime.h>
#include <math.h>

// Problem constants (match reference)
constexpr int kB   = 2;
constexpr int kT   = 2048;
constexpr int kDIN = 2048;
constexpr int kD   = 512;
constexpr int kH   = 8;
constexpr int kHD  = 64;
constexpr int kNB  = 2;
constexpr int kM   = kB * kT;   // 4096 rows
constexpr int kT2  = 2112;      // keys padded to 33*64 (2048 seq + 3 adapter + pad)
constexpr int kNT  = 33;        // key tiles of 64

using bf16x8 = __attribute__((ext_vector_type(8))) short;   // 8 bf16 (4 VGPRs)
using f32x4  = __attribute__((ext_vector_type(4))) float;   // 4 fp32 acc

__device__ inline ushort f2bf(float x) {        // fp32 -> bf16 RNE
    uint u = __float_as_uint(x);
    u = (u + 0x7fffu + ((u >> 16) & 1u)) >> 16;
    return (ushort)u;
}
__device__ inline uint pack2(float a, float b) {
    return (uint)f2bf(a) | ((uint)f2bf(b) << 16);
}

// ---------------------------------------------------------------------------
// Rope table: tab[(t*32+f)*2] = cos(t * 10000^(-f/32)), [..+1] = sin(...)
// ---------------------------------------------------------------------------
__global__ __launch_bounds__(256) void rope_table_kernel(float* __restrict__ tab) {
    int idx = blockIdx.x * blockDim.x + threadIdx.x; // t*32 + f
    if (idx >= kT * 32) return;
    int t = idx >> 5, f = idx & 31;
    double inv = pow(10000.0, -(double)f / 32.0);
    double ang = (double)t * inv;
    tab[idx * 2]     = (float)cos(ang);
    tab[idx * 2 + 1] = (float)sin(ang);
}

// ---------------------------------------------------------------------------
// Per-row mean / rstd for LayerNorm. One 256-thread block per row.
// ---------------------------------------------------------------------------
__global__ __launch_bounds__(256) void row_stats_kernel(const float* __restrict__ A,
                                                        float* __restrict__ stats, int C) {
    int row = blockIdx.x;
    const float4* A4 = (const float4*)(A + (size_t)row * C);
    int nv = C >> 2;
    float s = 0.f, ss = 0.f;
    for (int i = threadIdx.x; i < nv; i += 256) {
        float4 v = A4[i];
        s  += v.x + v.y + v.z + v.w;
        ss += v.x * v.x + v.y * v.y + v.z * v.z + v.w * v.w;
    }
    #pragma unroll
    for (int o = 32; o > 0; o >>= 1) {
        s  += __shfl_down(s, o, 64);
        ss += __shfl_down(ss, o, 64);
    }
    __shared__ float ls[4], lss[4];
    int wid = threadIdx.x >> 6, lane = threadIdx.x & 63;
    if (lane == 0) { ls[wid] = s; lss[wid] = ss; }
    __syncthreads();
    if (threadIdx.x == 0) {
        float S = ls[0] + ls[1] + ls[2] + ls[3];
        float SS = lss[0] + lss[1] + lss[2] + lss[3];
        float mean = S / C;
        float var  = SS / C - mean * mean;
        stats[row * 2]     = mean;
        stats[row * 2 + 1] = rsqrtf(var + 1e-5f);
    }
}

// ---------------------------------------------------------------------------
// Weight transpose+pack: W[K][N] fp32 -> Wt[N][K] bf16, 64x64 tiles via LDS.
// ---------------------------------------------------------------------------
__device__ inline void tp_tile(const float* __restrict__ src, ushort* __restrict__ dst,
                               int K, int N, int k0, int n0, float (*tile)[65]) {
    int tid = threadIdx.x;
    #pragma unroll
    for (int i = 0; i < 4; ++i) {
        int idx = tid + i * 256;
        int r = idx >> 4, c4 = (idx & 15) << 2;
        float4 v = *(const float4*)(src + (size_t)(k0 + r) * N + n0 + c4);
        tile[r][c4 + 0] = v.x; tile[r][c4 + 1] = v.y;
        tile[r][c4 + 2] = v.z; tile[r][c4 + 3] = v.w;
    }
    __syncthreads();
    int d = tid >> 2, kc = (tid & 3) * 16;
    uint* outp = (uint*)(dst + (size_t)(n0 + d) * K + k0 + kc);
    #pragma unroll
    for (int j = 0; j < 8; ++j)
        outp[j] = pack2(tile[kc + 2 * j][d], tile[kc + 2 * j + 1][d]);
}

__global__ __launch_bounds__(256) void wt_pack_fc1_kernel(
    const float* __restrict__ W, ushort* __restrict__ Wt) {
    __shared__ float tile[64][65];
    tp_tile(W, Wt, kDIN, kD, blockIdx.x * 64, blockIdx.y * 64, tile);
}

// z = wsel*2 + blk; wsel: 0=q 1=ks 2=vs 3=o 4=f. dst slab z: [512][512] bf16.
__global__ __launch_bounds__(256) void wt_pack_blocks_kernel(
    const float* __restrict__ qW, const float* __restrict__ ksW,
    const float* __restrict__ vsW, const float* __restrict__ oW,
    const float* __restrict__ fW, ushort* __restrict__ Wt) {
    __shared__ float tile[64][65];
    int z = blockIdx.z, wsel = z >> 1, blk = z & 1;
    const float* src;
    switch (wsel) {
        case 0: src = qW; break;
        case 1: src = ksW; break;
        case 2: src = vsW; break;
        case 3: src = oW; break;
        default: src = fW; break;
    }
    src += (size_t)blk * kD * kD;
    ushort* dst = Wt + (size_t)z * kD * kD;
    tp_tile(src, dst, kD, kD, blockIdx.x * 64, blockIdx.y * 64, tile);
}

// ---------------------------------------------------------------------------
// bf16 MFMA GEMM: C[M][N] = act( LN_opt(A) @ W + bias (+ res) ), fp32 in/out.
// Wt is pre-transposed bf16 [N][K]. BM=64, BN=128, BK=32; 4 waves (2m x 2n),
// each wave 32x64 output via 8x mfma_f32_16x16x32_bf16 per K-step.
// A converted fp32->bf16 (with fused LN) during LDS staging.
// Chunk swizzle s' = s ^ ((row>>2)&3) on both write & read (same involution;
// bounds frag-read conflicts at 2-way = free).
// ---------------------------------------------------------------------------
template <bool LN, bool RELU, bool RES>
__global__ __launch_bounds__(256) void gemm_mfma_kernel(
    const float* __restrict__ A, const ushort* __restrict__ Wt,
    const float* __restrict__ bias, const float* __restrict__ stats,
    const float* __restrict__ lnG, const float* __restrict__ lnB,
    const float* __restrict__ res, float* __restrict__ Cout,
    int K, int N) {
    __shared__ ushort As[64 * 32];    // [m][k] 4KB
    __shared__ ushort Bs[128 * 32];   // [n][k] 8KB
    int tid = threadIdx.x;
    int l = tid & 63;
    int l15 = l & 15, lg = l >> 4;
    int w = tid >> 6, wm = w >> 1, wn = w & 1;
    int m0 = blockIdx.y * 64, n0 = blockIdx.x * 128;

    // A staging: row ar (64), chunk aq (8 fp32 -> 8 bf16 = one uint4)
    int ar = tid >> 2, aq = tid & 3;
    float mean = 0.f, rstd = 0.f;
    if (LN) { mean = stats[(m0 + ar) * 2]; rstd = stats[(m0 + ar) * 2 + 1]; }
    const float* arow_p = A + (size_t)(m0 + ar) * K + aq * 8;
    ushort* as_w = As + ar * 32 + ((aq ^ ((ar >> 2) & 3)) * 8);

    // B staging: row br (128), half bh2 (2 chunks of 8 bf16)
    int br = tid >> 1, bh2 = tid & 1;
    const ushort* brow_p = Wt + (size_t)(n0 + br) * K + bh2 * 16;
    int bsw = (br >> 2) & 3;
    ushort* bs_w0 = Bs + br * 32 + (((bh2 * 2    ) ^ bsw) * 8);
    ushort* bs_w1 = Bs + br * 32 + (((bh2 * 2 + 1) ^ bsw) * 8);

    f32x4 acc[2][4];
    #pragma unroll
    for (int mf = 0; mf < 2; ++mf)
        #pragma unroll
        for (int nf = 0; nf < 4; ++nf) acc[mf][nf] = (f32x4){0.f, 0.f, 0.f, 0.f};

    for (int k0 = 0; k0 < K; k0 += 32) {
        __syncthreads();   // protect LDS from previous-iteration readers
        {   // stage A (fused LN + bf16 pack)
            float4 v0 = *(const float4*)(arow_p + k0);
            float4 v1 = *(const float4*)(arow_p + k0 + 4);
            if (LN) {
                float4 g0 = *(const float4*)(lnG + k0 + aq * 8);
                float4 g1 = *(const float4*)(lnG + k0 + aq * 8 + 4);
                float4 b0 = *(const float4*)(lnB + k0 + aq * 8);
                float4 b1 = *(const float4*)(lnB + k0 + aq * 8 + 4);
                v0.x = (v0.x - mean) * rstd * g0.x + b0.x;
                v0.y = (v0.y - mean) * rstd * g0.y + b0.y;
                v0.z = (v0.z - mean) * rstd * g0.z + b0.z;
                v0.w = (v0.w - mean) * rstd * g0.w + b0.w;
                v1.x = (v1.x - mean) * rstd * g1.x + b1.x;
                v1.y = (v1.y - mean) * rstd * g1.y + b1.y;
                v1.z = (v1.z - mean) * rstd * g1.z + b1.z;
                v1.w = (v1.w - mean) * rstd * g1.w + b1.w;
            }
            uint4 o;
            o.x = pack2(v0.x, v0.y); o.y = pack2(v0.z, v0.w);
            o.z = pack2(v1.x, v1.y); o.w = pack2(v1.z, v1.w);
            *(uint4*)as_w = o;
        }
        {   // stage B (already bf16, 32B per thread)
            const uint4* src = (const uint4*)(brow_p + k0);
            *(uint4*)bs_w0 = src[0];
            *(uint4*)bs_w1 = src[1];
        }
        __syncthreads();

        bf16x8 af[2], bf[4];
        #pragma unroll
        for (int mf = 0; mf < 2; ++mf) {
            int row = wm * 32 + mf * 16 + l15;
            af[mf] = *(const bf16x8*)(As + row * 32 + ((lg ^ ((row >> 2) & 3)) * 8));
        }
        #pragma unroll
        for (int nf = 0; nf < 4; ++nf) {
            int row = wn * 64 + nf * 16 + l15;
            bf[nf] = *(const bf16x8*)(Bs + row * 32 + ((lg ^ ((row >> 2) & 3)) * 8));
        }
        #pragma unroll
        for (int mf = 0; mf < 2; ++mf)
            #pragma unroll
            for (int nf = 0; nf < 4; ++nf)
                acc[mf][nf] = __builtin_amdgcn_mfma_f32_16x16x32_bf16(
                    af[mf], bf[nf], acc[mf][nf], 0, 0, 0);
    }

    // epilogue: row m = m0 + wm*32 + mf*16 + lg*4 + r ; col n = n0 + wn*64 + nf*16 + l15
    #pragma unroll
    for (int mf = 0; mf < 2; ++mf) {
        #pragma unroll
        for (int r = 0; r < 4; ++r) {
            int row = m0 + wm * 32 + mf * 16 + lg * 4 + r;
            float* crow = Cout + (size_t)row * N;
            const float* rrow = RES ? (res + (size_t)row * N) : nullptr;
            #pragma unroll
            for (int nf = 0; nf < 4; ++nf) {
                int col = n0 + wn * 64 + nf * 16 + l15;
                float c = acc[mf][nf][r] + bias[col];
                if (RES) c += rrow[col];
                if (RELU) c = fmaxf(c, 0.f);
                crow[col] = c;
            }
        }
    }
}

// ---------------------------------------------------------------------------
// fp32 GEMM (fc2 only, N=32): C = LN(A) @ W + bias
// ---------------------------------------------------------------------------
template <bool LN, bool RELU, bool RES>
__global__ __launch_bounds__(256) void gemm_kernel(
    const float* __restrict__ A, const float* __restrict__ W,
    const float* __restrict__ bias, const float* __restrict__ stats,
    const float* __restrict__ lnG, const float* __restrict__ lnB,
    const float* __restrict__ res, float* __restrict__ Cout,
    int K, int N) {
    __shared__ __align__(16) float As[16][68];
    __shared__ __align__(16) float Bs[16][68];
    int tid = threadIdx.x;
    int bm = blockIdx.y, bn = blockIdx.x;
    int tm = tid >> 4, tn = tid & 15;

    int am   = tid >> 2;
    int ak4  = (tid & 3) << 2;
    int arow = bm * 64 + am;
    float mean = 0.f, rstd = 0.f;
    if (LN) { mean = stats[arow * 2]; rstd = stats[arow * 2 + 1]; }

    int bk   = tid >> 4;
    int bn4  = (tid & 15) << 2;
    int bcol = bn * 64 + bn4;

    float acc[4][4] = {};

    for (int k0 = 0; k0 < K; k0 += 16) {
        float4 a = *(const float4*)(A + (size_t)arow * K + k0 + ak4);
        if (LN) {
            float4 gv = *(const float4*)(lnG + k0 + ak4);
            float4 bv = *(const float4*)(lnB + k0 + ak4);
            a.x = (a.x - mean) * rstd * gv.x + bv.x;
            a.y = (a.y - mean) * rstd * gv.y + bv.y;
            a.z = (a.z - mean) * rstd * gv.z + bv.z;
            a.w = (a.w - mean) * rstd * gv.w + bv.w;
        }
        As[ak4 + 0][am] = a.x;
        As[ak4 + 1][am] = a.y;
        As[ak4 + 2][am] = a.z;
        As[ak4 + 3][am] = a.w;

        float4 b = make_float4(0.f, 0.f, 0.f, 0.f);
        if (bcol < N) b = *(const float4*)(W + (size_t)(k0 + bk) * N + bcol);
        *(float4*)&Bs[bk][bn4] = b;

        __syncthreads();
        #pragma unroll
        for (int kk = 0; kk < 16; ++kk) {
            float4 av = *(const float4*)&As[kk][tm << 2];
            float4 bv = *(const float4*)&Bs[kk][tn << 2];
            acc[0][0] += av.x * bv.x; acc[0][1] += av.x * bv.y; acc[0][2] += av.x * bv.z; acc[0][3] += av.x * bv.w;
            acc[1][0] += av.y * bv.x; acc[1][1] += av.y * bv.y; acc[1][2] += av.y * bv.z; acc[1][3] += av.y * bv.w;
            acc[2][0] += av.z * bv.x; acc[2][1] += av.z * bv.y; acc[2][2] += av.z * bv.z; acc[2][3] += av.z * bv.w;
            acc[3][0] += av.w * bv.x; acc[3][1] += av.w * bv.y; acc[3][2] += av.w * bv.z; acc[3][3] += av.w * bv.w;
        }
        __syncthreads();
    }

    int crow0 = bm * 64 + (tm << 2);
    int ccol0 = bn * 64 + (tn << 2);
    if (ccol0 < N) {
        float4 bs = *(const float4*)(bias + ccol0);
        #pragma unroll
        for (int i = 0; i < 4; ++i) {
            float4 c = make_float4(acc[i][0] + bs.x, acc[i][1] + bs.y,
                                   acc[i][2] + bs.z, acc[i][3] + bs.w);
            if (RES) {
                float4 r = *(const float4*)(res + (size_t)(crow0 + i) * N + ccol0);
                c.x += r.x; c.y += r.y; c.z += r.z; c.w += r.w;
            }
            if (RELU) {
                c.x = fmaxf(c.x, 0.f); c.y = fmaxf(c.y, 0.f);
                c.z = fmaxf(c.z, 0.f); c.w = fmaxf(c.w, 0.f);
            }
            *(float4*)(Cout + (size_t)(crow0 + i) * N + ccol0) = c;
        }
    }
}

// ---------------------------------------------------------------------------
// Rope + bf16 pack into head-major layouts:
//   Qb[b][h][t][64] (scaled by 0.125 — exact in bf16), Kb[b][h][t (of kT2)][64]
// ---------------------------------------------------------------------------
__global__ __launch_bounds__(256) void rope_pack_kernel(
    const float* __restrict__ q, const float* __restrict__ k,
    const float* __restrict__ tab,
    ushort* __restrict__ Qb, ushort* __restrict__ Kb) {
    int idx = blockIdx.x * blockDim.x + threadIdx.x;  // pair index
    if (idx >= kM * (kD / 2)) return;
    int row = idx >> 8;
    int pi  = idx & 255;
    int col = pi << 1;
    int b = row >> 11, t = row & (kT - 1);
    int h = col >> 6, hd = col & 63;
    int dl = col & 63;
    int f0 = (dl < 32) ? dl : dl - 32;
    int f1 = f0 + 1;
    const float* tb = tab + (size_t)t * 64;
    float c0 = tb[f0 * 2], s0 = tb[f0 * 2 + 1];
    float c1 = tb[f1 * 2], s1 = tb[f1 * 2 + 1];
    size_t g = (size_t)row * kD + col;
    float2 qv = *(const float2*)(q + g);
    float2 kv = *(const float2*)(k + g);
    float qx = (qv.x * c0 - qv.y * s0) * 0.125f;
    float qy = (qv.y * c1 + qv.x * s1) * 0.125f;
    float kx = kv.x * c0 - kv.y * s0;
    float ky = kv.y * c1 + kv.x * s1;
    size_t qo = ((size_t)(b * kH + h) * kT  + t) * 64 + hd;
    size_t ko = ((size_t)(b * kH + h) * kT2 + t) * 64 + hd;
    *(uint*)(Qb + qo) = pack2(qx, qy);
    *(uint*)(Kb + ko) = pack2(kx, ky);
}

// ---------------------------------------------------------------------------
// V transpose + bf16 pack: Vtb[b][h][d (64)][t (kT2)].
// ---------------------------------------------------------------------------
__global__ __launch_bounds__(256) void vt_pack_kernel(
    const float* __restrict__ v, ushort* __restrict__ Vtb) {
    __shared__ float tile[64][65];
    int t0 = blockIdx.x * 64, h = blockIdx.y, b = blockIdx.z;
    int tid = threadIdx.x;
    #pragma unroll
    for (int i = 0; i < 4; ++i) {
        int idx = tid + i * 256;
        int r = idx >> 4, c4 = (idx & 15) << 2;
        float4 val = *(const float4*)(v + ((size_t)(b * kT + t0 + r)) * kD + h * kHD + c4);
        tile[r][c4 + 0] = val.x; tile[r][c4 + 1] = val.y;
        tile[r][c4 + 2] = val.z; tile[r][c4 + 3] = val.w;
    }
    __syncthreads();
    int d = tid >> 2, tc = (tid & 3) * 16;
    size_t base = ((size_t)(b * kH + h) * kHD + d) * kT2 + t0 + tc;
    uint* outp = (uint*)(Vtb + base);
    #pragma unroll
    for (int j = 0; j < 8; ++j)
        outp[j] = pack2(tile[tc + 2 * j][d], tile[tc + 2 * j + 1][d]);
}

// ---------------------------------------------------------------------------
// Adapter K/V rows (fp32 GEMVs): ka(2 rows, ka1 roped t=1), va(2), kt*tanh(g), vt
// ---------------------------------------------------------------------------
__global__ __launch_bounds__(256) void adapter_kernel(
    const float* __restrict__ h_a, const float* __restrict__ h_t, const float* __restrict__ p,
    const float* __restrict__ kaW, const float* __restrict__ kab,
    const float* __restrict__ vaW, const float* __restrict__ vab,
    const float* __restrict__ ktW, const float* __restrict__ ktb,
    const float* __restrict__ vtW, const float* __restrict__ vtb,
    const float* __restrict__ gscal, const float* __restrict__ tab,
    float* __restrict__ ka, float* __restrict__ va,
    float* __restrict__ kt, float* __restrict__ vt, int blk) {
    __shared__ float in[kD];
    int wg = blockIdx.x;
    int b = wg / 6, which = wg % 6;
    const float* ha_row = h_a + ((size_t)b * (kNB + 1) + blk + 1) * kD;
    const float* ht_row = h_t + ((size_t)b * (kNB + 1) + blk + 1) * kD;
    const float* p_row  = p + (size_t)b * kD;
    const float* inrow; const float* W; const float* bias; float* outrow;
    switch (which) {
        case 0: inrow = ha_row; W = kaW; bias = kab; outrow = ka + (size_t)(b * 2 + 0) * kD; break;
        case 1: inrow = p_row;  W = kaW; bias = kab; outrow = ka + (size_t)(b * 2 + 1) * kD; break;
        case 2: inrow = ha_row; W = vaW; bias = vab; outrow = va + (size_t)(b * 2 + 0) * kD; break;
        case 3: inrow = p_row;  W = vaW; bias = vab; outrow = va + (size_t)(b * 2 + 1) * kD; break;
        case 4: inrow = ht_row; W = ktW; bias = ktb; outrow = kt + (size_t)b * kD; break;
        default: inrow = ht_row; W = vtW; bias = vtb; outrow = vt + (size_t)b * kD; break;
    }
    W += (size_t)blk * kD * kD;
    bias += (size_t)blk * kD;
    int tid = threadIdx.x;
    in[tid * 2]     = inrow[tid * 2];
    in[tid * 2 + 1] = inrow[tid * 2 + 1];
    __syncthreads();
    float a0 = 0.f, a1 = 0.f;
    int c0 = tid * 2;
    for (int kk = 0; kk < kD; ++kk) {
        float x = in[kk];
        float2 w = *(const float2*)(W + (size_t)kk * kD + c0);
        a0 += x * w.x; a1 += x * w.y;
    }
    a0 += bias[c0]; a1 += bias[c0 + 1];
    if (which == 1) {
        int dl = c0 & 63;
        int f0 = (dl < 32) ? dl : dl - 32;
        int f1 = f0 + 1;
        const float* tb = tab + (size_t)1 * 64;
        float cc0 = tb[f0 * 2], ss0 = tb[f0 * 2 + 1];
        float cc1 = tb[f1 * 2], ss1 = tb[f1 * 2 + 1];
        float n0 = a0 * cc0 - a1 * ss0;
        float n1 = a1 * cc1 + a0 * ss1;
        a0 = n0; a1 = n1;
    }
    if (which == 4) {
        float r = tanhf(gscal[blk]);
        a0 *= r; a1 *= r;
    }
    outrow[c0] = a0; outrow[c0 + 1] = a1;
}

// ---------------------------------------------------------------------------
// Tail pack: Kb rows 2048..2111 (ka0, ka1, kt, zeros) and Vtb cols 2048..2111
// (va0, va1, vt, zeros), bf16. 16 blocks (b*8+h).
// ---------------------------------------------------------------------------
__global__ __launch_bounds__(256) void tailpack_kernel(
    const float* __restrict__ ka, const float* __restrict__ va,
    const float* __restrict__ ktp, const float* __restrict__ vtp,
    ushort* __restrict__ Kb, ushort* __restrict__ Vtb) {
    int bh = blockIdx.x; int b = bh >> 3, h = bh & 7;
    int tid = threadIdx.x;
    // K tail rows
    {
        int row = tid >> 2, dc = (tid & 3) * 16;
        const float* src = nullptr;
        if (row < 2)       src = ka  + (size_t)(b * 2 + row) * kD + h * kHD;
        else if (row == 2) src = ktp + (size_t)b * kD + h * kHD;
        size_t off = ((size_t)(b * kH + h) * kT2 + 2048 + row) * 64 + dc;
        uint* outp = (uint*)(Kb + off);
        #pragma unroll
        for (int j = 0; j < 8; ++j) {
            float a0 = src ? src[dc + 2 * j]     : 0.f;
            float a1 = src ? src[dc + 2 * j + 1] : 0.f;
            outp[j] = pack2(a0, a1);
        }
    }
    // Vt tail cols
    {
        int d = tid >> 2, kc = (tid & 3) * 16;
        float v0 = va[(size_t)(b * 2 + 0) * kD + h * kHD + d];
        float v1 = va[(size_t)(b * 2 + 1) * kD + h * kHD + d];
        float v2 = vtp[(size_t)b * kD + h * kHD + d];
        size_t off = ((size_t)(b * kH + h) * kHD + d) * kT2 + 2048 + kc;
        uint* outp = (uint*)(Vtb + off);
        #pragma unroll
        for (int j = 0; j < 8; ++j) {
            int k0 = kc + 2 * j, k1 = k0 + 1;
            float a0 = (k0 == 0) ? v0 : (k0 == 1) ? v1 : (k0 == 2) ? v2 : 0.f;
            float a1 = (k1 == 1) ? v1 : (k1 == 2) ? v2 : 0.f;
            outp[j] = pack2(a0, a1);
        }
    }
}

// ---------------------------------------------------------------------------
// MFMA flash attention. Grid (kT/64, H, B), 256 threads (4 waves x 16 q).
// ---------------------------------------------------------------------------
__global__ __launch_bounds__(256) void attn_mfma_kernel(
    const ushort* __restrict__ Qb, const ushort* __restrict__ Kb,
    const ushort* __restrict__ Vtb, float* __restrict__ out) {
    __shared__ ushort Ks[64 * 64];
    __shared__ ushort Vts[64 * 64];
    __shared__ ushort Ps[4][16 * 64];
    int tid = threadIdx.x;
    int w = tid >> 6, l = tid & 63;
    int l15 = l & 15, lg = l >> 4;
    int h = blockIdx.y, b = blockIdx.z;
    int tq0 = blockIdx.x * 64;
    const size_t bh = (size_t)(b * kH + h);

    // Q fragments: row q = l15 (wave-local), d = lg*8+j (+32 for frag 1)
    const ushort* qptr = Qb + (bh * kT + tq0 + w * 16 + l15) * 64 + lg * 8;
    bf16x8 qf0 = *(const bf16x8*)(qptr);
    bf16x8 qf1 = *(const bf16x8*)(qptr + 32);

    float m_run[4], l_run[4];
    #pragma unroll
    for (int r = 0; r < 4; ++r) { m_run[r] = -1e30f; l_run[r] = 0.f; }
    f32x4 acc[4];
    #pragma unroll
    for (int dt = 0; dt < 4; ++dt) acc[dt] = (f32x4){0.f, 0.f, 0.f, 0.f};

    ushort* Pw = Ps[w];
    const int swzr = (l15 & 7) << 4;   // read swizzle for rows indexed by l15

    for (int tile = 0; tile < kNT; ++tile) {
        __syncthreads();   // protect K/V LDS from previous-iteration readers
        {   // stage K tile
            int r = tid >> 2, c = tid & 3;
            const uint4* src = (const uint4*)(Kb + (bh * kT2 + (size_t)tile * 64 + r) * 64 + c * 16);
            uint4 v0 = src[0], v1 = src[1];
            int sw = (r & 7) << 4;
            char* dst = (char*)Ks + r * 128;
            *(uint4*)(dst + ((c * 32)      ^ sw)) = v0;
            *(uint4*)(dst + ((c * 32 + 16) ^ sw)) = v1;
        }
        {   // stage Vt tile (rows = d, cols = keys)
            int r = tid >> 2, c = tid & 3;
            const uint4* src = (const uint4*)(Vtb + (bh * kHD + r) * kT2 + (size_t)tile * 64 + c * 16);
            uint4 v0 = src[0], v1 = src[1];
            int sw = (r & 7) << 4;
            char* dst = (char*)Vts + r * 128;
            *(uint4*)(dst + ((c * 32)      ^ sw)) = v0;
            *(uint4*)(dst + ((c * 32 + 16) ^ sw)) = v1;
        }
        __syncthreads();

        // QK^T: 4 key subtiles, K=64 via 2 chained MFMAs
        f32x4 s[4];
        #pragma unroll
        for (int kt = 0; kt < 4; ++kt) {
            const char* krow = (const char*)Ks + (kt * 16 + l15) * 128;
            bf16x8 kf0 = *(const bf16x8*)(krow + ((lg * 16)      ^ swzr));
            bf16x8 kf1 = *(const bf16x8*)(krow + ((64 + lg * 16) ^ swzr));
            f32x4 z = (f32x4){0.f, 0.f, 0.f, 0.f};
            z = __builtin_amdgcn_mfma_f32_16x16x32_bf16(qf0, kf0, z, 0, 0, 0);
            z = __builtin_amdgcn_mfma_f32_16x16x32_bf16(qf1, kf1, z, 0, 0, 0);
            s[kt] = z;
        }
        if (tile == kNT - 1) {          // mask pad keys (>= 2051)
            #pragma unroll
            for (int kt = 0; kt < 4; ++kt) {
                int key = 2048 + kt * 16 + l15;
                if (key >= 2051) {
                    #pragma unroll
                    for (int r = 0; r < 4; ++r) s[kt][r] = -1e30f;
                }
            }
        }

        // online softmax: lane holds q = lg*4+r (4 rows), key = kt*16+l15
        float mr[4];
        #pragma unroll
        for (int r = 0; r < 4; ++r)
            mr[r] = fmaxf(fmaxf(s[0][r], s[1][r]), fmaxf(s[2][r], s[3][r]));
        #pragma unroll
        for (int mk = 1; mk < 16; mk <<= 1) {
            #pragma unroll
            for (int r = 0; r < 4; ++r) mr[r] = fmaxf(mr[r], __shfl_xor(mr[r], mk, 64));
        }
        float alpha[4], ps[4];
        #pragma unroll
        for (int r = 0; r < 4; ++r) {
            float nm = fmaxf(m_run[r], mr[r]);
            alpha[r] = __expf(m_run[r] - nm);
            m_run[r] = nm;
            ps[r] = 0.f;
        }
        #pragma unroll
        for (int kt = 0; kt < 4; ++kt) {
            #pragma unroll
            for (int r = 0; r < 4; ++r) {
                float pv = __expf(s[kt][r] - m_run[r]);
                s[kt][r] = pv;
                ps[r] += pv;
            }
        }
        #pragma unroll
        for (int mk = 1; mk < 16; mk <<= 1) {
            #pragma unroll
            for (int r = 0; r < 4; ++r) ps[r] += __shfl_xor(ps[r], mk, 64);
        }
        #pragma unroll
        for (int r = 0; r < 4; ++r) l_run[r] = l_run[r] * alpha[r] + ps[r];
        #pragma unroll
        for (int dt = 0; dt < 4; ++dt) {
            #pragma unroll
            for (int r = 0; r < 4; ++r) acc[dt][r] *= alpha[r];
        }

        // P (D-layout) -> per-wave LDS (A-layout source), bf16, swizzled
        #pragma unroll
        for (int kt = 0; kt < 4; ++kt) {
            #pragma unroll
            for (int r = 0; r < 4; ++r) {
                int qq = lg * 4 + r;
                int byteoff = qq * 128 + (((kt * 16 + l15) * 2) ^ ((qq & 7) << 4));
                *(ushort*)((char*)Pw + byteoff) = f2bf(s[kt][r]);
            }
        }
        // per-wave private: lgkmcnt orders within wave
        bf16x8 pf0 = *(const bf16x8*)((const char*)Pw + l15 * 128 + ((lg * 16)      ^ swzr));
        bf16x8 pf1 = *(const bf16x8*)((const char*)Pw + l15 * 128 + ((64 + lg * 16) ^ swzr));
        #pragma unroll
        for (int dt = 0; dt < 4; ++dt) {
            const char* vrow = (const char*)Vts + (dt * 16 + l15) * 128;
            bf16x8 vf0 = *(const bf16x8*)(vrow + ((lg * 16)      ^ swzr));
            bf16x8 vf1 = *(const bf16x8*)(vrow + ((64 + lg * 16) ^ swzr));
            acc[dt] = __builtin_amdgcn_mfma_f32_16x16x32_bf16(pf0, vf0, acc[dt], 0, 0, 0);
            acc[dt] = __builtin_amdgcn_mfma_f32_16x16x32_bf16(pf1, vf1, acc[dt], 0, 0, 0);
        }
    }

    // epilogue: O[q][d] = acc / l ; lane: q = lg*4+r, d = dt*16+l15
    #pragma unroll
    for (int r = 0; r < 4; ++r) {
        float inv = 1.f / l_run[r];
        int t = tq0 + w * 16 + lg * 4 + r;
        float* orow = out + ((size_t)(b * kT + t)) * kD + h * kHD;
        #pragma unroll
        for (int dt = 0; dt < 4; ++dt)
            orow[dt * 16 + l15] = acc[dt][r] * inv;
    }
}

// ---------------------------------------------------------------------------
extern "C" void kernel_launch(void* const* d_in, const int* in_sizes, int n_in,
                              void* d_out, int out_size, void* d_ws, size_t ws_size,
                              hipStream_t stream) {
    const float* x      = (const float*)d_in[0];
    const float* h_a    = (const float*)d_in[1];
    const float* h_t    = (const float*)d_in[2];
    const float* p      = (const float*)d_in[3];
    const float* ln1_g  = (const float*)d_in[4];
    const float* ln1_b  = (const float*)d_in[5];
    const float* fc1_W  = (const float*)d_in[6];
    const float* fc1_b  = (const float*)d_in[7];
    const float* blk_qW  = (const float*)d_in[8];
    const float* blk_qb  = (const float*)d_in[9];
    const float* blk_ksW = (const float*)d_in[10];
    const float* blk_ksb = (const float*)d_in[11];
    const float* blk_vsW = (const float*)d_in[12];
    const float* blk_vsb = (const float*)d_in[13];
    const float* blk_kaW = (const float*)d_in[14];
    const float* blk_kab = (const float*)d_in[15];
    const float* blk_vaW = (const float*)d_in[16];
    const float* blk_vab = (const float*)d_in[17];
    const float* blk_ktW = (const float*)d_in[18];
    const float* blk_ktb = (const float*)d_in[19];
    const float* blk_vtW = (const float*)d_in[20];
    const float* blk_vtb = (const float*)d_in[21];
    const float* blk_oW  = (const float*)d_in[22];
    const float* blk_ob  = (const float*)d_in[23];
    const float* blk_g   = (const float*)d_in[24];
    const float* blk_lnG = (const float*)d_in[25];
    const float* blk_lnB = (const float*)d_in[26];
    const float* blk_fW  = (const float*)d_in[27];
    const float* blk_fb  = (const float*)d_in[28];
    const float* ln2_g  = (const float*)d_in[29];
    const float* ln2_b  = (const float*)d_in[30];
    const float* fc2_W  = (const float*)d_in[31];
    const float* fc2_b  = (const float*)d_in[32];
    float* out = (float*)d_out;

    // Workspace layout (float units; all offsets multiples of 1024 floats).
    float* ws = (float*)d_ws;
    size_t o = 0;
    float* rope_tab = ws + o; o += (size_t)kT * 32 * 2;
    float* stats    = ws + o; o += (size_t)kM * 2;
    float* bufX     = ws + o; o += (size_t)kM * kD;
    float* bufQ     = ws + o; o += (size_t)kM * kD;   // also attention output
    float* bufK     = ws + o; o += (size_t)kM * kD;
    float* bufV     = ws + o; o += (size_t)kM * kD;   // also y (o-proj out)
    float* ka_buf   = ws + o; o += (size_t)kB * 2 * kD;
    float* va_buf   = ws + o; o += (size_t)kB * 2 * kD;
    float* kt_buf   = ws + o; o += (size_t)kB * kD;
    float* vt_buf   = ws + o; o += (size_t)kB * kD;
    ushort* Qb  = (ushort*)(ws + o); o += (size_t)kB * kH * kT  * kHD / 2;
    ushort* Kb  = (ushort*)(ws + o); o += (size_t)kB * kH * kT2 * kHD / 2;
    ushort* Vtb = (ushort*)(ws + o); o += (size_t)kB * kH * kT2 * kHD / 2;
    ushort* Wt_fc1 = (ushort*)(ws + o); o += (size_t)kD * kDIN / 2;
    ushort* Wt_blk = (ushort*)(ws + o); o += (size_t)10 * kD * kD / 2;

    dim3 blk256(256);
    dim3 mf_grid(kD / 128, kM / 64);      // (4, 64) for N=512 MFMA GEMMs
    dim3 fc2_grid(1, kM / 64);            // N=32 fp32
    dim3 attn_grid(kT / 64, kH, kB);      // (32, 8, 2)
    dim3 vtp_grid(kT / 64, kH, kB);
    dim3 tp_fc1_grid(kDIN / 64, kD / 64);    // (32, 8)
    dim3 tp_blk_grid(kD / 64, kD / 64, 10);  // (8, 8, 10)

    rope_table_kernel<<<(kT * 32 + 255) / 256, blk256, 0, stream>>>(rope_tab);

    // weight transpose+pack (once per call)
    wt_pack_fc1_kernel<<<tp_fc1_grid, blk256, 0, stream>>>(fc1_W, Wt_fc1);
    wt_pack_blocks_kernel<<<tp_blk_grid, blk256, 0, stream>>>(
        blk_qW, blk_ksW, blk_vsW, blk_oW, blk_fW, Wt_blk);

    // fc1: relu(LN(x) @ fc1_W + fc1_b)
    row_stats_kernel<<<kM, blk256, 0, stream>>>(x, stats, kDIN);
    gemm_mfma_kernel<true, true, false><<<mf_grid, blk256, 0, stream>>>(
        x, Wt_fc1, fc1_b, stats, ln1_g, ln1_b, nullptr, bufX, kDIN, kD);

    for (int blk = 0; blk < kNB; ++blk) {
        const size_t wsz = (size_t)kD * kD;
        const ushort* qWt  = Wt_blk + (0 * 2 + blk) * wsz;
        const ushort* ksWt = Wt_blk + (1 * 2 + blk) * wsz;
        const ushort* vsWt = Wt_blk + (2 * 2 + blk) * wsz;
        const ushort* oWt  = Wt_blk + (3 * 2 + blk) * wsz;
        const ushort* fWt  = Wt_blk + (4 * 2 + blk) * wsz;
        const float* qb  = blk_qb  + (size_t)blk * kD;
        const float* ksb = blk_ksb + (size_t)blk * kD;
        const float* vsb = blk_vsb + (size_t)blk * kD;
        const float* ob  = blk_ob  + (size_t)blk * kD;
        const float* fb  = blk_fb  + (size_t)blk * kD;
        const float* lnG = blk_lnG + (size_t)blk * kD;
        const float* lnB = blk_lnB + (size_t)blk * kD;

        // QKV projections (bf16 MFMA)
        gemm_mfma_kernel<false, false, false><<<mf_grid, blk256, 0, stream>>>(
            bufX, qWt, qb, nullptr, nullptr, nullptr, nullptr, bufQ, kD, kD);
        gemm_mfma_kernel<false, false, false><<<mf_grid, blk256, 0, stream>>>(
            bufX, ksWt, ksb, nullptr, nullptr, nullptr, nullptr, bufK, kD, kD);
        gemm_mfma_kernel<false, false, false><<<mf_grid, blk256, 0, stream>>>(
            bufX, vsWt, vsb, nullptr, nullptr, nullptr, nullptr, bufV, kD, kD);

        rope_pack_kernel<<<kM, blk256, 0, stream>>>(bufQ, bufK, rope_tab, Qb, Kb);
        vt_pack_kernel<<<vtp_grid, blk256, 0, stream>>>(bufV, Vtb);

        adapter_kernel<<<12, blk256, 0, stream>>>(
            h_a, h_t, p, blk_kaW, blk_kab, blk_vaW, blk_vab,
            blk_ktW, blk_ktb, blk_vtW, blk_vtb, blk_g, rope_tab,
            ka_buf, va_buf, kt_buf, vt_buf, blk);
        tailpack_kernel<<<16, blk256, 0, stream>>>(
            ka_buf, va_buf, kt_buf, vt_buf, Kb, Vtb);

        // attention -> bufQ (fp32 Q is dead; Qb holds staged Q)
        attn_mfma_kernel<<<attn_grid, blk256, 0, stream>>>(Qb, Kb, Vtb, bufQ);

        // o-proj + residual: y = AO @ oW + ob + x  -> bufV (V fp32 dead)
        gemm_mfma_kernel<false, false, true><<<mf_grid, blk256, 0, stream>>>(
            bufQ, oWt, ob, nullptr, nullptr, nullptr, bufX, bufV, kD, kD);

        // FFN: x = relu(LN(y) @ fW + fb)
        row_stats_kernel<<<kM, blk256, 0, stream>>>(bufV, stats, kD);
        gemm_mfma_kernel<true, true, false><<<mf_grid, blk256, 0, stream>>>(
            bufV, fWt, fb, stats, lnG, lnB, nullptr, bufX, kD, kD);
    }

    // final: LN(x) @ fc2_W + fc2_b  (fp32, N=32)
    row_stats_kernel<<<kM, blk256, 0, stream>>>(bufX, stats, kD);
    gemm_kernel<true, false, false><<<fc2_grid, blk256, 0, stream>>>(
        bufX, fc2_W, fc2_b, stats, ln2_g, ln2_b, nullptr, out, kD, 32);
}

// Round 10
// 572.233 us; speedup vs baseline: 2.9604x; 1.0910x over previous
//
#include <hip/hip_runtime.h>
#include <math.h>

// Problem constants (match reference)
constexpr int kB   = 2;
constexpr int kT   = 2048;
constexpr int kDIN = 2048;
constexpr int kD   = 512;
constexpr int kH   = 8;
constexpr int kHD  = 64;
constexpr int kNB  = 2;
constexpr int kM   = kB * kT;   // 4096 rows
constexpr int kT2  = 2112;      // keys padded to 33*64 (2048 seq + 3 adapter + pad)
constexpr int kNT  = 33;        // key tiles of 64

using bf16x8 = __attribute__((ext_vector_type(8))) short;   // 8 bf16 (4 VGPRs)
using f32x4  = __attribute__((ext_vector_type(4))) float;   // 4 fp32 acc

__device__ inline ushort f2bf(float x) {        // fp32 -> bf16 RNE
    uint u = __float_as_uint(x);
    u = (u + 0x7fffu + ((u >> 16) & 1u)) >> 16;
    return (ushort)u;
}
__device__ inline uint pack2(float a, float b) {
    return (uint)f2bf(a) | ((uint)f2bf(b) << 16);
}

// ---------------------------------------------------------------------------
// Rope table: tab[(t*32+f)*2] = cos(t * 10000^(-f/32)), [..+1] = sin(...)
// ---------------------------------------------------------------------------
__global__ __launch_bounds__(256) void rope_table_kernel(float* __restrict__ tab) {
    int idx = blockIdx.x * blockDim.x + threadIdx.x; // t*32 + f
    if (idx >= kT * 32) return;
    int t = idx >> 5, f = idx & 31;
    double inv = pow(10000.0, -(double)f / 32.0);
    double ang = (double)t * inv;
    tab[idx * 2]     = (float)cos(ang);
    tab[idx * 2 + 1] = (float)sin(ang);
}

// ---------------------------------------------------------------------------
// Per-row mean / rstd for LayerNorm. One 256-thread block per row.
// ---------------------------------------------------------------------------
__global__ __launch_bounds__(256) void row_stats_kernel(const float* __restrict__ A,
                                                        float* __restrict__ stats, int C) {
    int row = blockIdx.x;
    const float4* A4 = (const float4*)(A + (size_t)row * C);
    int nv = C >> 2;
    float s = 0.f, ss = 0.f;
    for (int i = threadIdx.x; i < nv; i += 256) {
        float4 v = A4[i];
        s  += v.x + v.y + v.z + v.w;
        ss += v.x * v.x + v.y * v.y + v.z * v.z + v.w * v.w;
    }
    #pragma unroll
    for (int o = 32; o > 0; o >>= 1) {
        s  += __shfl_down(s, o, 64);
        ss += __shfl_down(ss, o, 64);
    }
    __shared__ float ls[4], lss[4];
    int wid = threadIdx.x >> 6, lane = threadIdx.x & 63;
    if (lane == 0) { ls[wid] = s; lss[wid] = ss; }
    __syncthreads();
    if (threadIdx.x == 0) {
        float S = ls[0] + ls[1] + ls[2] + ls[3];
        float SS = lss[0] + lss[1] + lss[2] + lss[3];
        float mean = S / C;
        float var  = SS / C - mean * mean;
        stats[row * 2]     = mean;
        stats[row * 2 + 1] = rsqrtf(var + 1e-5f);
    }
}

// ---------------------------------------------------------------------------
// Weight transpose+pack: W[K][N] fp32 -> Wt[N][K] bf16, 64x64 tiles via LDS.
// ---------------------------------------------------------------------------
__device__ inline void tp_tile(const float* __restrict__ src, ushort* __restrict__ dst,
                               int K, int N, int k0, int n0, float (*tile)[65]) {
    int tid = threadIdx.x;
    #pragma unroll
    for (int i = 0; i < 4; ++i) {
        int idx = tid + i * 256;
        int r = idx >> 4, c4 = (idx & 15) << 2;
        float4 v = *(const float4*)(src + (size_t)(k0 + r) * N + n0 + c4);
        tile[r][c4 + 0] = v.x; tile[r][c4 + 1] = v.y;
        tile[r][c4 + 2] = v.z; tile[r][c4 + 3] = v.w;
    }
    __syncthreads();
    int d = tid >> 2, kc = (tid & 3) * 16;
    uint* outp = (uint*)(dst + (size_t)(n0 + d) * K + k0 + kc);
    #pragma unroll
    for (int j = 0; j < 8; ++j)
        outp[j] = pack2(tile[kc + 2 * j][d], tile[kc + 2 * j + 1][d]);
}

__global__ __launch_bounds__(256) void wt_pack_fc1_kernel(
    const float* __restrict__ W, ushort* __restrict__ Wt) {
    __shared__ float tile[64][65];
    tp_tile(W, Wt, kDIN, kD, blockIdx.x * 64, blockIdx.y * 64, tile);
}

// z = wsel*2 + blk; wsel: 0=q 1=ks 2=vs 3=o 4=f. dst slab z: [512][512] bf16.
__global__ __launch_bounds__(256) void wt_pack_blocks_kernel(
    const float* __restrict__ qW, const float* __restrict__ ksW,
    const float* __restrict__ vsW, const float* __restrict__ oW,
    const float* __restrict__ fW, ushort* __restrict__ Wt) {
    __shared__ float tile[64][65];
    int z = blockIdx.z, wsel = z >> 1, blk = z & 1;
    const float* src;
    switch (wsel) {
        case 0: src = qW; break;
        case 1: src = ksW; break;
        case 2: src = vsW; break;
        case 3: src = oW; break;
        default: src = fW; break;
    }
    src += (size_t)blk * kD * kD;
    ushort* dst = Wt + (size_t)z * kD * kD;
    tp_tile(src, dst, kD, kD, blockIdx.x * 64, blockIdx.y * 64, tile);
}

// ---------------------------------------------------------------------------
// bf16 MFMA GEMM. BM=BN=64, BK=64, 4 waves (2m x 2n), each wave 32x32 via
// 8x mfma_f32_16x16x32_bf16 per K-step. Wt pre-transposed bf16 [N][K].
// AMODE: 0 = A already bf16 [M][K]; 1 = A fp32 (pack in staging);
//        2 = A fp32 + fused LN (stats/lnG/lnB).
// LDS rows are 128B (64 bf16); 16B-chunk slot-XOR s^=(row&7) on BOTH the
// staging write and frag read (same involution) -> 8 consecutive lanes hit
// 8 distinct slots = conflict-free (attn-kernel-proven pattern, SQ_LDS=0).
// Epilogue: +bias (+res) (relu); write fp32 Cout and optionally bf16 Cb.
// ---------------------------------------------------------------------------
template <int AMODE, bool RELU, bool RES, bool DUAL>
__global__ __launch_bounds__(256) void gemm_bf16_kernel(
    const float* __restrict__ Af, const ushort* __restrict__ Ab,
    const ushort* __restrict__ Wt, const float* __restrict__ bias,
    const float* __restrict__ stats, const float* __restrict__ lnG,
    const float* __restrict__ lnB, const float* __restrict__ res,
    float* __restrict__ Cout, ushort* __restrict__ Cb, int K, int N) {
    __shared__ ushort As[64 * 64];    // 8KB
    __shared__ ushort Bs[64 * 64];    // 8KB
    int tid = threadIdx.x;
    int l15 = tid & 15, lg = (tid >> 4) & 3;
    int w = tid >> 6, wm = w >> 1, wn = w & 1;
    int m0 = blockIdx.y * 64, n0 = blockIdx.x * 64;

    // staging: row ar (0..63), chunk pair {aq, aq+4} (16B chunks of 8 bf16)
    int ar = tid >> 2, aq = tid & 3;
    float mean = 0.f, rstd = 0.f;
    if (AMODE == 2) { mean = stats[(m0 + ar) * 2]; rstd = stats[(m0 + ar) * 2 + 1]; }
    ushort* as_w0 = As + ar * 64 + (( aq      ^ (ar & 7)) * 8);
    ushort* as_w1 = As + ar * 64 + (((aq + 4) ^ (ar & 7)) * 8);
    ushort* bs_w0 = Bs + ar * 64 + (( aq      ^ (ar & 7)) * 8);
    ushort* bs_w1 = Bs + ar * 64 + (((aq + 4) ^ (ar & 7)) * 8);
    const ushort* brow = Wt + (size_t)(n0 + ar) * K;

    f32x4 acc[2][2];
    #pragma unroll
    for (int mf = 0; mf < 2; ++mf)
        #pragma unroll
        for (int nf = 0; nf < 2; ++nf) acc[mf][nf] = (f32x4){0.f, 0.f, 0.f, 0.f};

    for (int k0 = 0; k0 < K; k0 += 64) {
        __syncthreads();
        // stage A
        if (AMODE == 0) {
            const uint4* s = (const uint4*)(Ab + (size_t)(m0 + ar) * K + k0) + aq;
            *(uint4*)as_w0 = s[0];
            *(uint4*)as_w1 = s[4];
        } else {
            const float* ap = Af + (size_t)(m0 + ar) * K + k0 + aq * 8;
            float4 v0 = *(const float4*)(ap);
            float4 v1 = *(const float4*)(ap + 4);
            float4 v2 = *(const float4*)(ap + 32);
            float4 v3 = *(const float4*)(ap + 36);
            if (AMODE == 2) {
                const float* gp = lnG + k0 + aq * 8;
                const float* bp = lnB + k0 + aq * 8;
                float4 g0 = *(const float4*)(gp),      g1 = *(const float4*)(gp + 4);
                float4 g2 = *(const float4*)(gp + 32), g3 = *(const float4*)(gp + 36);
                float4 b0 = *(const float4*)(bp),      b1 = *(const float4*)(bp + 4);
                float4 b2 = *(const float4*)(bp + 32), b3 = *(const float4*)(bp + 36);
                v0.x = (v0.x - mean) * rstd * g0.x + b0.x; v0.y = (v0.y - mean) * rstd * g0.y + b0.y;
                v0.z = (v0.z - mean) * rstd * g0.z + b0.z; v0.w = (v0.w - mean) * rstd * g0.w + b0.w;
                v1.x = (v1.x - mean) * rstd * g1.x + b1.x; v1.y = (v1.y - mean) * rstd * g1.y + b1.y;
                v1.z = (v1.z - mean) * rstd * g1.z + b1.z; v1.w = (v1.w - mean) * rstd * g1.w + b1.w;
                v2.x = (v2.x - mean) * rstd * g2.x + b2.x; v2.y = (v2.y - mean) * rstd * g2.y + b2.y;
                v2.z = (v2.z - mean) * rstd * g2.z + b2.z; v2.w = (v2.w - mean) * rstd * g2.w + b2.w;
                v3.x = (v3.x - mean) * rstd * g3.x + b3.x; v3.y = (v3.y - mean) * rstd * g3.y + b3.y;
                v3.z = (v3.z - mean) * rstd * g3.z + b3.z; v3.w = (v3.w - mean) * rstd * g3.w + b3.w;
            }
            uint4 o0, o1;
            o0.x = pack2(v0.x, v0.y); o0.y = pack2(v0.z, v0.w);
            o0.z = pack2(v1.x, v1.y); o0.w = pack2(v1.z, v1.w);
            o1.x = pack2(v2.x, v2.y); o1.y = pack2(v2.z, v2.w);
            o1.z = pack2(v3.x, v3.y); o1.w = pack2(v3.z, v3.w);
            *(uint4*)as_w0 = o0;
            *(uint4*)as_w1 = o1;
        }
        // stage B (bf16 copy)
        {
            const uint4* s = (const uint4*)(brow + k0) + aq;
            *(uint4*)bs_w0 = s[0];
            *(uint4*)bs_w1 = s[4];
        }
        __syncthreads();

        #pragma unroll
        for (int kk = 0; kk < 2; ++kk) {
            bf16x8 af[2], bfr[2];
            #pragma unroll
            for (int mf = 0; mf < 2; ++mf) {
                int row = wm * 32 + mf * 16 + l15;
                af[mf] = *(const bf16x8*)(As + row * 64 + (((kk * 4 + lg) ^ (row & 7)) * 8));
            }
            #pragma unroll
            for (int nf = 0; nf < 2; ++nf) {
                int row = wn * 32 + nf * 16 + l15;
                bfr[nf] = *(const bf16x8*)(Bs + row * 64 + (((kk * 4 + lg) ^ (row & 7)) * 8));
            }
            #pragma unroll
            for (int mf = 0; mf < 2; ++mf)
                #pragma unroll
                for (int nf = 0; nf < 2; ++nf)
                    acc[mf][nf] = __builtin_amdgcn_mfma_f32_16x16x32_bf16(
                        af[mf], bfr[nf], acc[mf][nf], 0, 0, 0);
        }
    }

    // epilogue: row = m0+wm*32+mf*16+lg*4+r ; col = n0+wn*32+nf*16+l15
    #pragma unroll
    for (int mf = 0; mf < 2; ++mf) {
        #pragma unroll
        for (int r = 0; r < 4; ++r) {
            int row = m0 + wm * 32 + mf * 16 + lg * 4 + r;
            float* crow = Cout + (size_t)row * N;
            ushort* cbrow = DUAL ? (Cb + (size_t)row * N) : nullptr;
            const float* rrow = RES ? (res + (size_t)row * N) : nullptr;
            #pragma unroll
            for (int nf = 0; nf < 2; ++nf) {
                int col = n0 + wn * 32 + nf * 16 + l15;
                float c = acc[mf][nf][r] + bias[col];
                if (RES) c += rrow[col];
                if (RELU) c = fmaxf(c, 0.f);
                crow[col] = c;
                if (DUAL) cbrow[col] = f2bf(c);
            }
        }
    }
}

// ---------------------------------------------------------------------------
// fp32 GEMM (fc2 only, N=32): C = LN(A) @ W + bias
// ---------------------------------------------------------------------------
template <bool LN, bool RELU, bool RES>
__global__ __launch_bounds__(256) void gemm_kernel(
    const float* __restrict__ A, const float* __restrict__ W,
    const float* __restrict__ bias, const float* __restrict__ stats,
    const float* __restrict__ lnG, const float* __restrict__ lnB,
    const float* __restrict__ res, float* __restrict__ Cout,
    int K, int N) {
    __shared__ __align__(16) float As[16][68];
    __shared__ __align__(16) float Bs[16][68];
    int tid = threadIdx.x;
    int bm = blockIdx.y, bn = blockIdx.x;
    int tm = tid >> 4, tn = tid & 15;

    int am   = tid >> 2;
    int ak4  = (tid & 3) << 2;
    int arow = bm * 64 + am;
    float mean = 0.f, rstd = 0.f;
    if (LN) { mean = stats[arow * 2]; rstd = stats[arow * 2 + 1]; }

    int bk   = tid >> 4;
    int bn4  = (tid & 15) << 2;
    int bcol = bn * 64 + bn4;

    float acc[4][4] = {};

    for (int k0 = 0; k0 < K; k0 += 16) {
        float4 a = *(const float4*)(A + (size_t)arow * K + k0 + ak4);
        if (LN) {
            float4 gv = *(const float4*)(lnG + k0 + ak4);
            float4 bv = *(const float4*)(lnB + k0 + ak4);
            a.x = (a.x - mean) * rstd * gv.x + bv.x;
            a.y = (a.y - mean) * rstd * gv.y + bv.y;
            a.z = (a.z - mean) * rstd * gv.z + bv.z;
            a.w = (a.w - mean) * rstd * gv.w + bv.w;
        }
        As[ak4 + 0][am] = a.x;
        As[ak4 + 1][am] = a.y;
        As[ak4 + 2][am] = a.z;
        As[ak4 + 3][am] = a.w;

        float4 b = make_float4(0.f, 0.f, 0.f, 0.f);
        if (bcol < N) b = *(const float4*)(W + (size_t)(k0 + bk) * N + bcol);
        *(float4*)&Bs[bk][bn4] = b;

        __syncthreads();
        #pragma unroll
        for (int kk = 0; kk < 16; ++kk) {
            float4 av = *(const float4*)&As[kk][tm << 2];
            float4 bv = *(const float4*)&Bs[kk][tn << 2];
            acc[0][0] += av.x * bv.x; acc[0][1] += av.x * bv.y; acc[0][2] += av.x * bv.z; acc[0][3] += av.x * bv.w;
            acc[1][0] += av.y * bv.x; acc[1][1] += av.y * bv.y; acc[1][2] += av.y * bv.z; acc[1][3] += av.y * bv.w;
            acc[2][0] += av.z * bv.x; acc[2][1] += av.z * bv.y; acc[2][2] += av.z * bv.z; acc[2][3] += av.z * bv.w;
            acc[3][0] += av.w * bv.x; acc[3][1] += av.w * bv.y; acc[3][2] += av.w * bv.z; acc[3][3] += av.w * bv.w;
        }
        __syncthreads();
    }

    int crow0 = bm * 64 + (tm << 2);
    int ccol0 = bn * 64 + (tn << 2);
    if (ccol0 < N) {
        float4 bs = *(const float4*)(bias + ccol0);
        #pragma unroll
        for (int i = 0; i < 4; ++i) {
            float4 c = make_float4(acc[i][0] + bs.x, acc[i][1] + bs.y,
                                   acc[i][2] + bs.z, acc[i][3] + bs.w);
            if (RES) {
                float4 r = *(const float4*)(res + (size_t)(crow0 + i) * N + ccol0);
                c.x += r.x; c.y += r.y; c.z += r.z; c.w += r.w;
            }
            if (RELU) {
                c.x = fmaxf(c.x, 0.f); c.y = fmaxf(c.y, 0.f);
                c.z = fmaxf(c.z, 0.f); c.w = fmaxf(c.w, 0.f);
            }
            *(float4*)(Cout + (size_t)(crow0 + i) * N + ccol0) = c;
        }
    }
}

// ---------------------------------------------------------------------------
// Rope + bf16 pack into head-major layouts:
//   Qb[b][h][t][64] (scaled by 0.125 — exact in bf16), Kb[b][h][t (of kT2)][64]
// ---------------------------------------------------------------------------
__global__ __launch_bounds__(256) void rope_pack_kernel(
    const float* __restrict__ q, const float* __restrict__ k,
    const float* __restrict__ tab,
    ushort* __restrict__ Qb, ushort* __restrict__ Kb) {
    int idx = blockIdx.x * blockDim.x + threadIdx.x;  // pair index
    if (idx >= kM * (kD / 2)) return;
    int row = idx >> 8;
    int pi  = idx & 255;
    int col = pi << 1;
    int b = row >> 11, t = row & (kT - 1);
    int h = col >> 6, hd = col & 63;
    int dl = col & 63;
    int f0 = (dl < 32) ? dl : dl - 32;
    int f1 = f0 + 1;
    const float* tb = tab + (size_t)t * 64;
    float c0 = tb[f0 * 2], s0 = tb[f0 * 2 + 1];
    float c1 = tb[f1 * 2], s1 = tb[f1 * 2 + 1];
    size_t g = (size_t)row * kD + col;
    float2 qv = *(const float2*)(q + g);
    float2 kv = *(const float2*)(k + g);
    float qx = (qv.x * c0 - qv.y * s0) * 0.125f;
    float qy = (qv.y * c1 + qv.x * s1) * 0.125f;
    float kx = kv.x * c0 - kv.y * s0;
    float ky = kv.y * c1 + kv.x * s1;
    size_t qo = ((size_t)(b * kH + h) * kT  + t) * 64 + hd;
    size_t ko = ((size_t)(b * kH + h) * kT2 + t) * 64 + hd;
    *(uint*)(Qb + qo) = pack2(qx, qy);
    *(uint*)(Kb + ko) = pack2(kx, ky);
}

// ---------------------------------------------------------------------------
// V transpose + bf16 pack: Vtb[b][h][d (64)][t (kT2)].
// ---------------------------------------------------------------------------
__global__ __launch_bounds__(256) void vt_pack_kernel(
    const float* __restrict__ v, ushort* __restrict__ Vtb) {
    __shared__ float tile[64][65];
    int t0 = blockIdx.x * 64, h = blockIdx.y, b = blockIdx.z;
    int tid = threadIdx.x;
    #pragma unroll
    for (int i = 0; i < 4; ++i) {
        int idx = tid + i * 256;
        int r = idx >> 4, c4 = (idx & 15) << 2;
        float4 val = *(const float4*)(v + ((size_t)(b * kT + t0 + r)) * kD + h * kHD + c4);
        tile[r][c4 + 0] = val.x; tile[r][c4 + 1] = val.y;
        tile[r][c4 + 2] = val.z; tile[r][c4 + 3] = val.w;
    }
    __syncthreads();
    int d = tid >> 2, tc = (tid & 3) * 16;
    size_t base = ((size_t)(b * kH + h) * kHD + d) * kT2 + t0 + tc;
    uint* outp = (uint*)(Vtb + base);
    #pragma unroll
    for (int j = 0; j < 8; ++j)
        outp[j] = pack2(tile[tc + 2 * j][d], tile[tc + 2 * j + 1][d]);
}

// ---------------------------------------------------------------------------
// Adapter K/V rows (fp32 GEMVs): ka(2 rows, ka1 roped t=1), va(2), kt*tanh(g), vt
// ---------------------------------------------------------------------------
__global__ __launch_bounds__(256) void adapter_kernel(
    const float* __restrict__ h_a, const float* __restrict__ h_t, const float* __restrict__ p,
    const float* __restrict__ kaW, const float* __restrict__ kab,
    const float* __restrict__ vaW, const float* __restrict__ vab,
    const float* __restrict__ ktW, const float* __restrict__ ktb,
    const float* __restrict__ vtW, const float* __restrict__ vtb,
    const float* __restrict__ gscal, const float* __restrict__ tab,
    float* __restrict__ ka, float* __restrict__ va,
    float* __restrict__ kt, float* __restrict__ vt, int blk) {
    __shared__ float in[kD];
    int wg = blockIdx.x;
    int b = wg / 6, which = wg % 6;
    const float* ha_row = h_a + ((size_t)b * (kNB + 1) + blk + 1) * kD;
    const float* ht_row = h_t + ((size_t)b * (kNB + 1) + blk + 1) * kD;
    const float* p_row  = p + (size_t)b * kD;
    const float* inrow; const float* W; const float* bias; float* outrow;
    switch (which) {
        case 0: inrow = ha_row; W = kaW; bias = kab; outrow = ka + (size_t)(b * 2 + 0) * kD; break;
        case 1: inrow = p_row;  W = kaW; bias = kab; outrow = ka + (size_t)(b * 2 + 1) * kD; break;
        case 2: inrow = ha_row; W = vaW; bias = vab; outrow = va + (size_t)(b * 2 + 0) * kD; break;
        case 3: inrow = p_row;  W = vaW; bias = vab; outrow = va + (size_t)(b * 2 + 1) * kD; break;
        case 4: inrow = ht_row; W = ktW; bias = ktb; outrow = kt + (size_t)b * kD; break;
        default: inrow = ht_row; W = vtW; bias = vtb; outrow = vt + (size_t)b * kD; break;
    }
    W += (size_t)blk * kD * kD;
    bias += (size_t)blk * kD;
    int tid = threadIdx.x;
    in[tid * 2]     = inrow[tid * 2];
    in[tid * 2 + 1] = inrow[tid * 2 + 1];
    __syncthreads();
    float a0 = 0.f, a1 = 0.f;
    int c0 = tid * 2;
    for (int kk = 0; kk < kD; ++kk) {
        float x = in[kk];
        float2 w = *(const float2*)(W + (size_t)kk * kD + c0);
        a0 += x * w.x; a1 += x * w.y;
    }
    a0 += bias[c0]; a1 += bias[c0 + 1];
    if (which == 1) {
        int dl = c0 & 63;
        int f0 = (dl < 32) ? dl : dl - 32;
        int f1 = f0 + 1;
        const float* tb = tab + (size_t)1 * 64;
        float cc0 = tb[f0 * 2], ss0 = tb[f0 * 2 + 1];
        float cc1 = tb[f1 * 2], ss1 = tb[f1 * 2 + 1];
        float n0 = a0 * cc0 - a1 * ss0;
        float n1 = a1 * cc1 + a0 * ss1;
        a0 = n0; a1 = n1;
    }
    if (which == 4) {
        float r = tanhf(gscal[blk]);
        a0 *= r; a1 *= r;
    }
    outrow[c0] = a0; outrow[c0 + 1] = a1;
}

// ---------------------------------------------------------------------------
// Tail pack: Kb rows 2048..2111 (ka0, ka1, kt, zeros) and Vtb cols 2048..2111
// (va0, va1, vt, zeros), bf16. 16 blocks (b*8+h).
// ---------------------------------------------------------------------------
__global__ __launch_bounds__(256) void tailpack_kernel(
    const float* __restrict__ ka, const float* __restrict__ va,
    const float* __restrict__ ktp, const float* __restrict__ vtp,
    ushort* __restrict__ Kb, ushort* __restrict__ Vtb) {
    int bh = blockIdx.x; int b = bh >> 3, h = bh & 7;
    int tid = threadIdx.x;
    // K tail rows
    {
        int row = tid >> 2, dc = (tid & 3) * 16;
        const float* src = nullptr;
        if (row < 2)       src = ka  + (size_t)(b * 2 + row) * kD + h * kHD;
        else if (row == 2) src = ktp + (size_t)b * kD + h * kHD;
        size_t off = ((size_t)(b * kH + h) * kT2 + 2048 + row) * 64 + dc;
        uint* outp = (uint*)(Kb + off);
        #pragma unroll
        for (int j = 0; j < 8; ++j) {
            float a0 = src ? src[dc + 2 * j]     : 0.f;
            float a1 = src ? src[dc + 2 * j + 1] : 0.f;
            outp[j] = pack2(a0, a1);
        }
    }
    // Vt tail cols
    {
        int d = tid >> 2, kc = (tid & 3) * 16;
        float v0 = va[(size_t)(b * 2 + 0) * kD + h * kHD + d];
        float v1 = va[(size_t)(b * 2 + 1) * kD + h * kHD + d];
        float v2 = vtp[(size_t)b * kD + h * kHD + d];
        size_t off = ((size_t)(b * kH + h) * kHD + d) * kT2 + 2048 + kc;
        uint* outp = (uint*)(Vtb + off);
        #pragma unroll
        for (int j = 0; j < 8; ++j) {
            int k0 = kc + 2 * j, k1 = k0 + 1;
            float a0 = (k0 == 0) ? v0 : (k0 == 1) ? v1 : (k0 == 2) ? v2 : 0.f;
            float a1 = (k1 == 1) ? v1 : (k1 == 2) ? v2 : 0.f;
            outp[j] = pack2(a0, a1);
        }
    }
}

// ---------------------------------------------------------------------------
// MFMA flash attention. Grid (kT/64, H, B), 256 threads (4 waves x 16 q).
// Async-stage split (T14): next tile's global loads issue right after the
// staging barrier and land in regs; they are consumed by the NEXT iteration's
// ds_write, so HBM latency hides under this iteration's QK/softmax/PV.
// Output written directly as bf16 (AOb) for the o-proj GEMM's A operand.
// ---------------------------------------------------------------------------
__global__ __launch_bounds__(256) void attn_mfma_kernel(
    const ushort* __restrict__ Qb, const ushort* __restrict__ Kb,
    const ushort* __restrict__ Vtb, ushort* __restrict__ AOb) {
    __shared__ ushort Ks[64 * 64];
    __shared__ ushort Vts[64 * 64];
    __shared__ ushort Ps[4][16 * 64];
    int tid = threadIdx.x;
    int w = tid >> 6, l = tid & 63;
    int l15 = l & 15, lg = l >> 4;
    int h = blockIdx.y, b = blockIdx.z;
    int tq0 = blockIdx.x * 64;
    const size_t bh = (size_t)(b * kH + h);

    // Q fragments: row q = l15 (wave-local), d = lg*8+j (+32 for frag 1)
    const ushort* qptr = Qb + (bh * kT + tq0 + w * 16 + l15) * 64 + lg * 8;
    bf16x8 qf0 = *(const bf16x8*)(qptr);
    bf16x8 qf1 = *(const bf16x8*)(qptr + 32);

    float m_run[4], l_run[4];
    #pragma unroll
    for (int r = 0; r < 4; ++r) { m_run[r] = -1e30f; l_run[r] = 0.f; }
    f32x4 acc[4];
    #pragma unroll
    for (int dt = 0; dt < 4; ++dt) acc[dt] = (f32x4){0.f, 0.f, 0.f, 0.f};

    ushort* Pw = Ps[w];
    const int swzr = (l15 & 7) << 4;   // read swizzle for rows indexed by l15

    // staging identity: row sr (0..63), 32B chunk sc (0..3)
    int sr = tid >> 2, sc = tid & 3;
    const int sw = (sr & 7) << 4;
    uint4 kra, krb, vra, vrb;
    {   // prologue: tile 0 loads
        const uint4* ks = (const uint4*)(Kb + (bh * kT2 + sr) * 64 + sc * 16);
        kra = ks[0]; krb = ks[1];
        const uint4* vs = (const uint4*)(Vtb + (bh * kHD + sr) * kT2 + sc * 16);
        vra = vs[0]; vrb = vs[1];
    }

    for (int tile = 0; tile < kNT; ++tile) {
        __syncthreads();   // previous-iteration LDS readers done
        {   // ds_write current tile from regs (vmcnt wait lands here)
            char* dk = (char*)Ks + sr * 128;
            *(uint4*)(dk + ((sc * 32)      ^ sw)) = kra;
            *(uint4*)(dk + ((sc * 32 + 16) ^ sw)) = krb;
            char* dv = (char*)Vts + sr * 128;
            *(uint4*)(dv + ((sc * 32)      ^ sw)) = vra;
            *(uint4*)(dv + ((sc * 32 + 16) ^ sw)) = vrb;
        }
        __syncthreads();
        if (tile + 1 < kNT) {   // issue next-tile loads; in flight during compute
            const uint4* ks = (const uint4*)(Kb + (bh * kT2 + (size_t)(tile + 1) * 64 + sr) * 64 + sc * 16);
            kra = ks[0]; krb = ks[1];
            const uint4* vs = (const uint4*)(Vtb + (bh * kHD + sr) * kT2 + (size_t)(tile + 1) * 64 + sc * 16);
            vra = vs[0]; vrb = vs[1];
        }

        // QK^T: 4 key subtiles, K=64 via 2 chained MFMAs
        f32x4 s[4];
        #pragma unroll
        for (int kt = 0; kt < 4; ++kt) {
            const char* krow = (const char*)Ks + (kt * 16 + l15) * 128;
            bf16x8 kf0 = *(const bf16x8*)(krow + ((lg * 16)      ^ swzr));
            bf16x8 kf1 = *(const bf16x8*)(krow + ((64 + lg * 16) ^ swzr));
            f32x4 z = (f32x4){0.f, 0.f, 0.f, 0.f};
            z = __builtin_amdgcn_mfma_f32_16x16x32_bf16(qf0, kf0, z, 0, 0, 0);
            z = __builtin_amdgcn_mfma_f32_16x16x32_bf16(qf1, kf1, z, 0, 0, 0);
            s[kt] = z;
        }
        if (tile == kNT - 1) {          // mask pad keys (>= 2051)
            #pragma unroll
            for (int kt = 0; kt < 4; ++kt) {
                int key = 2048 + kt * 16 + l15;
                if (key >= 2051) {
                    #pragma unroll
                    for (int r = 0; r < 4; ++r) s[kt][r] = -1e30f;
                }
            }
        }

        // online softmax: lane holds q = lg*4+r (4 rows), key = kt*16+l15
        float mr[4];
        #pragma unroll
        for (int r = 0; r < 4; ++r)
            mr[r] = fmaxf(fmaxf(s[0][r], s[1][r]), fmaxf(s[2][r], s[3][r]));
        #pragma unroll
        for (int mk = 1; mk < 16; mk <<= 1) {
            #pragma unroll
            for (int r = 0; r < 4; ++r) mr[r] = fmaxf(mr[r], __shfl_xor(mr[r], mk, 64));
        }
        float alpha[4], ps[4];
        #pragma unroll
        for (int r = 0; r < 4; ++r) {
            float nm = fmaxf(m_run[r], mr[r]);
            alpha[r] = __expf(m_run[r] - nm);
            m_run[r] = nm;
            ps[r] = 0.f;
        }
        #pragma unroll
        for (int kt = 0; kt < 4; ++kt) {
            #pragma unroll
            for (int r = 0; r < 4; ++r) {
                float pv = __expf(s[kt][r] - m_run[r]);
                s[kt][r] = pv;
                ps[r] += pv;
            }
        }
        #pragma unroll
        for (int mk = 1; mk < 16; mk <<= 1) {
            #pragma unroll
            for (int r = 0; r < 4; ++r) ps[r] += __shfl_xor(ps[r], mk, 64);
        }
        #pragma unroll
        for (int r = 0; r < 4; ++r) l_run[r] = l_run[r] * alpha[r] + ps[r];
        #pragma unroll
        for (int dt = 0; dt < 4; ++dt) {
            #pragma unroll
            for (int r = 0; r < 4; ++r) acc[dt][r] *= alpha[r];
        }

        // P (D-layout) -> per-wave LDS (A-layout source), bf16, swizzled
        #pragma unroll
        for (int kt = 0; kt < 4; ++kt) {
            #pragma unroll
            for (int r = 0; r < 4; ++r) {
                int qq = lg * 4 + r;
                int byteoff = qq * 128 + (((kt * 16 + l15) * 2) ^ ((qq & 7) << 4));
                *(ushort*)((char*)Pw + byteoff) = f2bf(s[kt][r]);
            }
        }
        // per-wave private: lgkmcnt orders within wave
        bf16x8 pf0 = *(const bf16x8*)((const char*)Pw + l15 * 128 + ((lg * 16)      ^ swzr));
        bf16x8 pf1 = *(const bf16x8*)((const char*)Pw + l15 * 128 + ((64 + lg * 16) ^ swzr));
        #pragma unroll
        for (int dt = 0; dt < 4; ++dt) {
            const char* vrow = (const char*)Vts + (dt * 16 + l15) * 128;
            bf16x8 vf0 = *(const bf16x8*)(vrow + ((lg * 16)      ^ swzr));
            bf16x8 vf1 = *(const bf16x8*)(vrow + ((64 + lg * 16) ^ swzr));
            acc[dt] = __builtin_amdgcn_mfma_f32_16x16x32_bf16(pf0, vf0, acc[dt], 0, 0, 0);
            acc[dt] = __builtin_amdgcn_mfma_f32_16x16x32_bf16(pf1, vf1, acc[dt], 0, 0, 0);
        }
    }

    // epilogue: AO[q][d] = acc / l, bf16 ; lane: q = lg*4+r, d = dt*16+l15
    #pragma unroll
    for (int r = 0; r < 4; ++r) {
        float inv = 1.f / l_run[r];
        int t = tq0 + w * 16 + lg * 4 + r;
        ushort* orow = AOb + ((size_t)(b * kT + t)) * kD + h * kHD;
        #pragma unroll
        for (int dt = 0; dt < 4; ++dt)
            orow[dt * 16 + l15] = f2bf(acc[dt][r] * inv);
    }
}

// ---------------------------------------------------------------------------
extern "C" void kernel_launch(void* const* d_in, const int* in_sizes, int n_in,
                              void* d_out, int out_size, void* d_ws, size_t ws_size,
                              hipStream_t stream) {
    const float* x      = (const float*)d_in[0];
    const float* h_a    = (const float*)d_in[1];
    const float* h_t    = (const float*)d_in[2];
    const float* p      = (const float*)d_in[3];
    const float* ln1_g  = (const float*)d_in[4];
    const float* ln1_b  = (const float*)d_in[5];
    const float* fc1_W  = (const float*)d_in[6];
    const float* fc1_b  = (const float*)d_in[7];
    const float* blk_qW  = (const float*)d_in[8];
    const float* blk_qb  = (const float*)d_in[9];
    const float* blk_ksW = (const float*)d_in[10];
    const float* blk_ksb = (const float*)d_in[11];
    const float* blk_vsW = (const float*)d_in[12];
    const float* blk_vsb = (const float*)d_in[13];
    const float* blk_kaW = (const float*)d_in[14];
    const float* blk_kab = (const float*)d_in[15];
    const float* blk_vaW = (const float*)d_in[16];
    const float* blk_vab = (const float*)d_in[17];
    const float* blk_ktW = (const float*)d_in[18];
    const float* blk_ktb = (const float*)d_in[19];
    const float* blk_vtW = (const float*)d_in[20];
    const float* blk_vtb = (const float*)d_in[21];
    const float* blk_oW  = (const float*)d_in[22];
    const float* blk_ob  = (const float*)d_in[23];
    const float* blk_g   = (const float*)d_in[24];
    const float* blk_lnG = (const float*)d_in[25];
    const float* blk_lnB = (const float*)d_in[26];
    const float* blk_fW  = (const float*)d_in[27];
    const float* blk_fb  = (const float*)d_in[28];
    const float* ln2_g  = (const float*)d_in[29];
    const float* ln2_b  = (const float*)d_in[30];
    const float* fc2_W  = (const float*)d_in[31];
    const float* fc2_b  = (const float*)d_in[32];
    float* out = (float*)d_out;

    // Workspace layout (float units). Total ~72 MB.
    float* ws = (float*)d_ws;
    size_t o = 0;
    float* rope_tab = ws + o; o += (size_t)kT * 32 * 2;
    float* stats    = ws + o; o += (size_t)kM * 2;
    float* bufX     = ws + o; o += (size_t)kM * kD;   // residual (fp32)
    float* bufQ     = ws + o; o += (size_t)kM * kD;
    float* bufK     = ws + o; o += (size_t)kM * kD;
    float* bufV     = ws + o; o += (size_t)kM * kD;   // also y (o-proj out)
    float* ka_buf   = ws + o; o += (size_t)kB * 2 * kD;
    float* va_buf   = ws + o; o += (size_t)kB * 2 * kD;
    float* kt_buf   = ws + o; o += (size_t)kB * kD;
    float* vt_buf   = ws + o; o += (size_t)kB * kD;
    ushort* Qb   = (ushort*)(ws + o); o += (size_t)kB * kH * kT  * kHD / 2;
    ushort* Kb   = (ushort*)(ws + o); o += (size_t)kB * kH * kT2 * kHD / 2;
    ushort* Vtb  = (ushort*)(ws + o); o += (size_t)kB * kH * kT2 * kHD / 2;
    ushort* Wt_fc1 = (ushort*)(ws + o); o += (size_t)kD * kDIN / 2;
    ushort* Wt_blk = (ushort*)(ws + o); o += (size_t)10 * kD * kD / 2;
    ushort* bufXb  = (ushort*)(ws + o); o += (size_t)kM * kD / 2;   // bf16 copy of x (QKV A)
    ushort* AOb    = (ushort*)(ws + o); o += (size_t)kM * kD / 2;   // bf16 attention out

    dim3 blk256(256);
    dim3 mf_grid(kD / 64, kM / 64);       // (8, 64) = 512 blocks, 2/CU
    dim3 fc2_grid(1, kM / 64);            // N=32 fp32
    dim3 attn_grid(kT / 64, kH, kB);      // (32, 8, 2)
    dim3 vtp_grid(kT / 64, kH, kB);
    dim3 tp_fc1_grid(kDIN / 64, kD / 64);    // (32, 8)
    dim3 tp_blk_grid(kD / 64, kD / 64, 10);  // (8, 8, 10)

    rope_table_kernel<<<(kT * 32 + 255) / 256, blk256, 0, stream>>>(rope_tab);

    // weight transpose+pack (once per call)
    wt_pack_fc1_kernel<<<tp_fc1_grid, blk256, 0, stream>>>(fc1_W, Wt_fc1);
    wt_pack_blocks_kernel<<<tp_blk_grid, blk256, 0, stream>>>(
        blk_qW, blk_ksW, blk_vsW, blk_oW, blk_fW, Wt_blk);

    // fc1: relu(LN(x) @ fc1_W + fc1_b) -> bufX fp32 + bufXb bf16
    row_stats_kernel<<<kM, blk256, 0, stream>>>(x, stats, kDIN);
    gemm_bf16_kernel<2, true, false, true><<<mf_grid, blk256, 0, stream>>>(
        x, nullptr, Wt_fc1, fc1_b, stats, ln1_g, ln1_b, nullptr,
        bufX, bufXb, kDIN, kD);

    for (int blk = 0; blk < kNB; ++blk) {
        const size_t wsz = (size_t)kD * kD;
        const ushort* qWt  = Wt_blk + (0 * 2 + blk) * wsz;
        const ushort* ksWt = Wt_blk + (1 * 2 + blk) * wsz;
        const ushort* vsWt = Wt_blk + (2 * 2 + blk) * wsz;
        const ushort* oWt  = Wt_blk + (3 * 2 + blk) * wsz;
        const ushort* fWt  = Wt_blk + (4 * 2 + blk) * wsz;
        const float* qb  = blk_qb  + (size_t)blk * kD;
        const float* ksb = blk_ksb + (size_t)blk * kD;
        const float* vsb = blk_vsb + (size_t)blk * kD;
        const float* ob  = blk_ob  + (size_t)blk * kD;
        const float* fb  = blk_fb  + (size_t)blk * kD;
        const float* lnG = blk_lnG + (size_t)blk * kD;
        const float* lnB = blk_lnB + (size_t)blk * kD;

        // QKV projections (bf16 A from bufXb)
        gemm_bf16_kernel<0, false, false, false><<<mf_grid, blk256, 0, stream>>>(
            nullptr, bufXb, qWt, qb, nullptr, nullptr, nullptr, nullptr,
            bufQ, nullptr, kD, kD);
        gemm_bf16_kernel<0, false, false, false><<<mf_grid, blk256, 0, stream>>>(
            nullptr, bufXb, ksWt, ksb, nullptr, nullptr, nullptr, nullptr,
            bufK, nullptr, kD, kD);
        gemm_bf16_kernel<0, false, false, false><<<mf_grid, blk256, 0, stream>>>(
            nullptr, bufXb, vsWt, vsb, nullptr, nullptr, nullptr, nullptr,
            bufV, nullptr, kD, kD);

        rope_pack_kernel<<<kM, blk256, 0, stream>>>(bufQ, bufK, rope_tab, Qb, Kb);
        vt_pack_kernel<<<vtp_grid, blk256, 0, stream>>>(bufV, Vtb);

        adapter_kernel<<<12, blk256, 0, stream>>>(
            h_a, h_t, p, blk_kaW, blk_kab, blk_vaW, blk_vab,
            blk_ktW, blk_ktb, blk_vtW, blk_vtb, blk_g, rope_tab,
            ka_buf, va_buf, kt_buf, vt_buf, blk);
        tailpack_kernel<<<16, blk256, 0, stream>>>(
            ka_buf, va_buf, kt_buf, vt_buf, Kb, Vtb);

        // attention -> AOb (bf16)
        attn_mfma_kernel<<<attn_grid, blk256, 0, stream>>>(Qb, Kb, Vtb, AOb);

        // o-proj + residual: y = AO @ oW + ob + x  -> bufV (fp32 V is dead)
        gemm_bf16_kernel<0, false, true, false><<<mf_grid, blk256, 0, stream>>>(
            nullptr, AOb, oWt, ob, nullptr, nullptr, nullptr, bufX,
            bufV, nullptr, kD, kD);

        // FFN: x = relu(LN(y) @ fW + fb) -> bufX fp32 + bufXb bf16
        row_stats_kernel<<<kM, blk256, 0, stream>>>(bufV, stats, kD);
        gemm_bf16_kernel<2, true, false, true><<<mf_grid, blk256, 0, stream>>>(
            bufV, nullptr, fWt, fb, stats, lnG, lnB, nullptr,
            bufX, bufXb, kD, kD);
    }

    // final: LN(x) @ fc2_W + fc2_b  (fp32, N=32)
    row_stats_kernel<<<kM, blk256, 0, stream>>>(bufX, stats, kD);
    gemm_kernel<true, false, false><<<fc2_grid, blk256, 0, stream>>>(
        bufX, fc2_W, fc2_b, stats, ln2_g, ln2_b, nullptr, out, kD, 32);
}